// Round 1
// baseline (4491.935 us; speedup 1.0000x reference)
//
#include <hip/hip_runtime.h>

#define CDIM 768
#define BATCH 8
#define LDEPTH 8
#define HHEIGHT 14
#define WWIDTH 14
#define NSP 1568      // 8*14*14 spatial tokens (input / q)
#define NQTOK 1569    // +cls
#define NKSP 392      // 8*7*7 spatial tokens (k/v after pool)
#define NKTOK 393
#define NHEADS 12
#define HEADDIM 64
#define ATTN_SCALE 0.125f
#define LN_EPS 1e-6f
#define MTOK (BATCH * NQTOK)   // 12552 tokens for proj GEMM

// ---------------------------------------------------------------------------
// GEMM 1: Out[b][m][n] = sum_k W[m][k] * X[b][k][n] + bias[m]
// W: (768,768) row-major. X: (B,768,1568). Out: (B,768,1568).
// 128x128 tile, 8x8 microtile, Ktile=16.
// ---------------------------------------------------------------------------
__global__ __launch_bounds__(256) void gemm_wx_kernel(
    const float* __restrict__ W, const float* __restrict__ X,
    const float* __restrict__ bias, float* __restrict__ Out) {
  __shared__ float As[16][132];
  __shared__ float Bs[16][132];
  const int b = blockIdx.z;
  const int m0 = blockIdx.y * 128;
  const int n0 = blockIdx.x * 128;
  const int tid = threadIdx.x;
  const int tx = tid & 15, ty = tid >> 4;
  const float* Xb = X + (size_t)b * ((size_t)CDIM * NSP);

  float acc[8][8];
#pragma unroll
  for (int i = 0; i < 8; i++)
#pragma unroll
    for (int j = 0; j < 8; j++) acc[i][j] = 0.f;

  for (int k0 = 0; k0 < CDIM; k0 += 16) {
#pragma unroll
    for (int i = 0; i < 8; i++) {
      int idx = tid + i * 256;
      int r = idx >> 4, c = idx & 15;          // r: 0..127 (m), c: 0..15 (k)
      As[c][r] = W[(size_t)(m0 + r) * CDIM + k0 + c];
    }
#pragma unroll
    for (int i = 0; i < 8; i++) {
      int idx = tid + i * 256;
      int r = idx >> 7, c = idx & 127;         // r: 0..15 (k), c: 0..127 (n)
      int n = n0 + c;
      Bs[r][c] = (n < NSP) ? Xb[(size_t)(k0 + r) * NSP + n] : 0.f;
    }
    __syncthreads();
#pragma unroll
    for (int k = 0; k < 16; k++) {
      float av[8], bv[8];
      *(float4*)&av[0] = *(const float4*)&As[k][ty * 4];
      *(float4*)&av[4] = *(const float4*)&As[k][64 + ty * 4];
      *(float4*)&bv[0] = *(const float4*)&Bs[k][tx * 4];
      *(float4*)&bv[4] = *(const float4*)&Bs[k][64 + tx * 4];
#pragma unroll
      for (int i = 0; i < 8; i++)
#pragma unroll
        for (int j = 0; j < 8; j++) acc[i][j] = fmaf(av[i], bv[j], acc[i][j]);
    }
    __syncthreads();
  }

#pragma unroll
  for (int i = 0; i < 8; i++) {
    int mrow = m0 + (i >> 2) * 64 + ty * 4 + (i & 3);
    float bia = bias[mrow];
    float* orow = Out + ((size_t)b * CDIM + mrow) * (size_t)NSP;
#pragma unroll
    for (int jq = 0; jq < 2; jq++) {
      int n = n0 + jq * 64 + tx * 4;
      if (n < NSP) {
        float4 v;
        v.x = acc[i][jq * 4 + 0] + bia;
        v.y = acc[i][jq * 4 + 1] + bia;
        v.z = acc[i][jq * 4 + 2] + bia;
        v.w = acc[i][jq * 4 + 3] + bia;
        *(float4*)&orow[n] = v;
      }
    }
  }
}

// ---------------------------------------------------------------------------
// cls token linear: out[b][co] = dot(cls[b,:], W[co,:]) + bias[co]
// grid = B, block = 256, each thread 3 outputs.
// ---------------------------------------------------------------------------
__global__ __launch_bounds__(256) void cls_linear_kernel(
    const float* __restrict__ cls, const float* __restrict__ W,
    const float* __restrict__ bias, float* __restrict__ out) {
  __shared__ float xs[CDIM];
  const int b = blockIdx.x;
  for (int i = threadIdx.x; i < CDIM; i += 256) xs[i] = cls[b * CDIM + i];
  __syncthreads();
#pragma unroll
  for (int cc = 0; cc < 3; cc++) {
    int co = threadIdx.x + cc * 256;
    const float* wr = W + (size_t)co * CDIM;
    float sum = bias[co];
    for (int k = 0; k < CDIM; k += 4) {
      float4 wv = *(const float4*)&wr[k];
      float4 xv = *(const float4*)&xs[k];
      sum = fmaf(wv.x, xv.x, sum);
      sum = fmaf(wv.y, xv.y, sum);
      sum = fmaf(wv.z, xv.z, sum);
      sum = fmaf(wv.w, xv.w, sum);
    }
    out[b * CDIM + co] = sum;
  }
}

// ---------------------------------------------------------------------------
// Depthwise 3x3x3 conv (stride 1 in L, sh/sw in H/W, pad 1) + LayerNorm over C.
// One block per (b, output position); 256 threads, 3 channels/thread.
// ---------------------------------------------------------------------------
__global__ __launch_bounds__(256) void pool_ln_kernel(
    const float* __restrict__ X, const float* __restrict__ wconv,
    const float* __restrict__ ln_w, const float* __restrict__ ln_b,
    float* __restrict__ Out, int Lo, int Ho, int Wo, int sh, int sw) {
  const int npos = Lo * Ho * Wo;
  const int pos = blockIdx.x % npos;
  const int b = blockIdx.x / npos;
  const int wo = pos % Wo;
  const int ho = (pos / Wo) % Ho;
  const int lo = pos / (Wo * Ho);
  const int li0 = lo - 1;
  const int hi0 = ho * sh - 1;
  const int wi0 = wo * sw - 1;

  float val[3];
#pragma unroll
  for (int cc = 0; cc < 3; cc++) {
    int c = threadIdx.x + cc * 256;
    const float* xb = X + ((size_t)b * CDIM + c) * (size_t)NSP;
    const float* wc = wconv + c * 27;
    float sum = 0.f;
#pragma unroll
    for (int kd = 0; kd < 3; kd++) {
      int li = li0 + kd;
      if (li < 0 || li >= LDEPTH) continue;
#pragma unroll
      for (int kh = 0; kh < 3; kh++) {
        int hi = hi0 + kh;
        if (hi < 0 || hi >= HHEIGHT) continue;
#pragma unroll
        for (int kw = 0; kw < 3; kw++) {
          int wi = wi0 + kw;
          if (wi < 0 || wi >= WWIDTH) continue;
          sum = fmaf(xb[(li * HHEIGHT + hi) * WWIDTH + wi],
                     wc[(kd * 3 + kh) * 3 + kw], sum);
        }
      }
    }
    val[cc] = sum;
  }

  float s1 = val[0] + val[1] + val[2];
  float s2 = val[0] * val[0] + val[1] * val[1] + val[2] * val[2];
#pragma unroll
  for (int off = 32; off > 0; off >>= 1) {
    s1 += __shfl_down(s1, off, 64);
    s2 += __shfl_down(s2, off, 64);
  }
  __shared__ float red[8];
  int wid = threadIdx.x >> 6;
  int lane = threadIdx.x & 63;
  if (lane == 0) { red[wid] = s1; red[wid + 4] = s2; }
  __syncthreads();
  float t1 = red[0] + red[1] + red[2] + red[3];
  float t2 = red[4] + red[5] + red[6] + red[7];
  float mean = t1 * (1.f / 768.f);
  float var = t2 * (1.f / 768.f) - mean * mean;
  float rstd = rsqrtf(var + LN_EPS);
#pragma unroll
  for (int cc = 0; cc < 3; cc++) {
    int c = threadIdx.x + cc * 256;
    Out[((size_t)b * CDIM + c) * (size_t)npos + pos] =
        (val[cc] - mean) * rstd * ln_w[c] + ln_b[c];
  }
}

// ---------------------------------------------------------------------------
// Flash attention. Grid (7, 12, 8). One thread = one q token (online softmax).
// K/V tiles of 64 tokens staged in LDS.
// o_flat: (B, 1569, 768) token-major.
// ---------------------------------------------------------------------------
__global__ __launch_bounds__(256) void attn_kernel(
    const float* __restrict__ qpool, const float* __restrict__ kpool,
    const float* __restrict__ vpool, const float* __restrict__ cls_q,
    const float* __restrict__ cls_k, const float* __restrict__ cls_v,
    float* __restrict__ o_flat) {
  __shared__ float lds_k[64 * 68];
  __shared__ float lds_v[64 * 68];
  const int b = blockIdx.z, h = blockIdx.y;
  const int nq = blockIdx.x * 256 + threadIdx.x;
  const bool active = nq < NQTOK;

  float q[64];
  if (active) {
    if (nq == 0) {
#pragma unroll
      for (int d = 0; d < 64; d++) q[d] = cls_q[b * CDIM + h * HEADDIM + d];
    } else {
#pragma unroll
      for (int d = 0; d < 64; d++)
        q[d] = qpool[(size_t)(b * CDIM + h * HEADDIM + d) * NSP + nq - 1];
    }
  } else {
#pragma unroll
    for (int d = 0; d < 64; d++) q[d] = 0.f;
  }

  float m = -1e30f, l = 0.f;
  float acc[64];
#pragma unroll
  for (int d = 0; d < 64; d++) acc[d] = 0.f;

  for (int kt = 0; kt < NKTOK; kt += 64) {
    const int count = min(64, NKTOK - kt);
    for (int i = threadIdx.x; i < 64 * 64; i += 256) {
      int t = i & 63, d = i >> 6;
      float kv = 0.f, vv = 0.f;
      int gt = kt + t;
      if (t < count) {
        if (gt == 0) {
          kv = cls_k[b * CDIM + h * HEADDIM + d];
          vv = cls_v[b * CDIM + h * HEADDIM + d];
        } else {
          size_t idx = (size_t)(b * CDIM + h * HEADDIM + d) * NKSP + gt - 1;
          kv = kpool[idx];
          vv = vpool[idx];
        }
      }
      lds_k[t * 68 + d] = kv;
      lds_v[t * 68 + d] = vv;
    }
    __syncthreads();
    if (active) {
      for (int cj = 0; cj < count; cj += 8) {
        int cn = min(8, count - cj);
        float s[8];
#pragma unroll
        for (int j = 0; j < 8; j++) {
          if (j < cn) {
            const float* kr = &lds_k[(cj + j) * 68];
            float sum = 0.f;
#pragma unroll
            for (int d4 = 0; d4 < 16; d4++) {
              float4 kv4 = *(const float4*)&kr[d4 * 4];
              sum = fmaf(q[d4 * 4 + 0], kv4.x, sum);
              sum = fmaf(q[d4 * 4 + 1], kv4.y, sum);
              sum = fmaf(q[d4 * 4 + 2], kv4.z, sum);
              sum = fmaf(q[d4 * 4 + 3], kv4.w, sum);
            }
            s[j] = sum * ATTN_SCALE;
          } else {
            s[j] = -1e30f;
          }
        }
        float cmax = s[0];
#pragma unroll
        for (int j = 1; j < 8; j++) cmax = fmaxf(cmax, s[j]);
        float mnew = fmaxf(m, cmax);
        float alpha = __expf(m - mnew);
        l *= alpha;
#pragma unroll
        for (int d = 0; d < 64; d++) acc[d] *= alpha;
#pragma unroll
        for (int j = 0; j < 8; j++) {
          if (j < cn) {
            float p = __expf(s[j] - mnew);
            l += p;
            const float* vr = &lds_v[(cj + j) * 68];
#pragma unroll
            for (int d = 0; d < 64; d++) acc[d] = fmaf(p, vr[d], acc[d]);
          }
        }
        m = mnew;
      }
    }
    __syncthreads();
  }

  if (active) {
    float inv = 1.f / l;
    float* op = &o_flat[((size_t)b * NQTOK + nq) * CDIM + h * HEADDIM];
#pragma unroll
    for (int d4 = 0; d4 < 16; d4++) {
      float4 o4;
      o4.x = acc[d4 * 4 + 0] * inv;
      o4.y = acc[d4 * 4 + 1] * inv;
      o4.z = acc[d4 * 4 + 2] * inv;
      o4.w = acc[d4 * 4 + 3] * inv;
      *(float4*)&op[d4 * 4] = o4;
    }
  }
}

// ---------------------------------------------------------------------------
// Projection GEMM: out[tok][co] = sum_k Wproj[co][k]*Tin[tok][k] + bias[co]
// Tin: (12552, 768) token-major. Scattered write into (xo, cls_o).
// ---------------------------------------------------------------------------
__global__ __launch_bounds__(256) void gemm_proj_kernel(
    const float* __restrict__ W, const float* __restrict__ Tin,
    const float* __restrict__ bias, float* __restrict__ xo,
    float* __restrict__ cls_o) {
  __shared__ float As[16][132];
  __shared__ float Bs[16][132];
  const int m0 = blockIdx.y * 128;   // c_out
  const int n0 = blockIdx.x * 128;   // token
  const int tid = threadIdx.x;
  const int tx = tid & 15, ty = tid >> 4;

  float acc[8][8];
#pragma unroll
  for (int i = 0; i < 8; i++)
#pragma unroll
    for (int j = 0; j < 8; j++) acc[i][j] = 0.f;

  for (int k0 = 0; k0 < CDIM; k0 += 16) {
#pragma unroll
    for (int i = 0; i < 8; i++) {
      int idx = tid + i * 256;
      int r = idx >> 4, c = idx & 15;
      As[c][r] = W[(size_t)(m0 + r) * CDIM + k0 + c];
    }
#pragma unroll
    for (int i = 0; i < 8; i++) {
      int idx = tid + i * 256;
      int tr = idx >> 4, c = idx & 15;  // tr: token-local 0..127, c: k 0..15
      int tok = n0 + tr;
      Bs[c][tr] = (tok < MTOK) ? Tin[(size_t)tok * CDIM + k0 + c] : 0.f;
    }
    __syncthreads();
#pragma unroll
    for (int k = 0; k < 16; k++) {
      float av[8], bv[8];
      *(float4*)&av[0] = *(const float4*)&As[k][ty * 4];
      *(float4*)&av[4] = *(const float4*)&As[k][64 + ty * 4];
      *(float4*)&bv[0] = *(const float4*)&Bs[k][tx * 4];
      *(float4*)&bv[4] = *(const float4*)&Bs[k][64 + tx * 4];
#pragma unroll
      for (int i = 0; i < 8; i++)
#pragma unroll
        for (int j = 0; j < 8; j++) acc[i][j] = fmaf(av[i], bv[j], acc[i][j]);
    }
    __syncthreads();
  }

#pragma unroll
  for (int i = 0; i < 8; i++) {
    int co = m0 + (i >> 2) * 64 + ty * 4 + (i & 3);
    float bia = bias[co];
#pragma unroll
    for (int j = 0; j < 8; j++) {
      int tok = n0 + (j >> 2) * 64 + tx * 4 + (j & 3);
      if (tok < MTOK) {
        int bb = tok / NQTOK;
        int nn = tok % NQTOK;
        float v = acc[i][j] + bia;
        if (nn == 0)
          cls_o[bb * CDIM + co] = v;
        else
          xo[((size_t)bb * CDIM + co) * (size_t)NSP + nn - 1] = v;
      }
    }
  }
}

// ---------------------------------------------------------------------------
extern "C" void kernel_launch(void* const* d_in, const int* in_sizes, int n_in,
                              void* d_out, int out_size, void* d_ws, size_t ws_size,
                              hipStream_t stream) {
  const float* x      = (const float*)d_in[0];
  const float* cls    = (const float*)d_in[1];
  const float* Wq     = (const float*)d_in[2];
  const float* bq     = (const float*)d_in[3];
  const float* Wk     = (const float*)d_in[4];
  const float* bk     = (const float*)d_in[5];
  const float* Wv     = (const float*)d_in[6];
  const float* bv     = (const float*)d_in[7];
  const float* conv_q = (const float*)d_in[8];
  const float* conv_k = (const float*)d_in[9];
  const float* conv_v = (const float*)d_in[10];
  const float* lnq_w  = (const float*)d_in[11];
  const float* lnq_b  = (const float*)d_in[12];
  const float* lnk_w  = (const float*)d_in[13];
  const float* lnk_b  = (const float*)d_in[14];
  const float* lnv_w  = (const float*)d_in[15];
  const float* lnv_b  = (const float*)d_in[16];
  const float* Wproj  = (const float*)d_in[17];
  const float* bproj  = (const float*)d_in[18];

  // Workspace layout (floats). Total = 43,370,496 floats = 173.5 MB.
  float* ws = (float*)d_ws;
  const size_t SZ_LIN = (size_t)BATCH * CDIM * NSP;     // 9,633,792
  const size_t SZ_KV  = (size_t)BATCH * CDIM * NKSP;    // 2,408,448
  const size_t SZ_CLS = (size_t)BATCH * CDIM;           // 6,144
  size_t off = 0;
  float* q_lin  = ws + off; off += SZ_LIN;
  float* q_pool = ws + off; off += SZ_LIN;
  float* k_pool = ws + off; off += SZ_KV;
  float* v_pool = ws + off; off += SZ_KV;
  float* clsq   = ws + off; off += SZ_CLS;
  float* clsk   = ws + off; off += SZ_CLS;
  float* clsv   = ws + off; off += SZ_CLS;
  float* k_lin  = ws + off; off += SZ_LIN;
  float* v_lin  = ws + off; off += SZ_LIN;
  // o_flat (9,639,936 floats) aliases k_lin (+ first 6,144 floats of v_lin),
  // both dead by the time attention runs.
  float* o_flat = k_lin;

  dim3 gw(13, 6, BATCH);   // ceil(1568/128)=13, 768/128=6
  gemm_wx_kernel<<<gw, 256, 0, stream>>>(Wq, x, bq, q_lin);
  gemm_wx_kernel<<<gw, 256, 0, stream>>>(Wk, x, bk, k_lin);
  gemm_wx_kernel<<<gw, 256, 0, stream>>>(Wv, x, bv, v_lin);

  cls_linear_kernel<<<BATCH, 256, 0, stream>>>(cls, Wq, bq, clsq);
  cls_linear_kernel<<<BATCH, 256, 0, stream>>>(cls, Wk, bk, clsk);
  cls_linear_kernel<<<BATCH, 256, 0, stream>>>(cls, Wv, bv, clsv);

  pool_ln_kernel<<<BATCH * NSP, 256, 0, stream>>>(q_lin, conv_q, lnq_w, lnq_b,
                                                  q_pool, 8, 14, 14, 1, 1);
  pool_ln_kernel<<<BATCH * NKSP, 256, 0, stream>>>(k_lin, conv_k, lnk_w, lnk_b,
                                                   k_pool, 8, 7, 7, 2, 2);
  pool_ln_kernel<<<BATCH * NKSP, 256, 0, stream>>>(v_lin, conv_v, lnv_w, lnv_b,
                                                   v_pool, 8, 7, 7, 2, 2);

  attn_kernel<<<dim3(7, NHEADS, BATCH), 256, 0, stream>>>(
      q_pool, k_pool, v_pool, clsq, clsk, clsv, o_flat);

  float* xo = (float*)d_out;
  float* cls_o = (float*)d_out + (size_t)BATCH * CDIM * NSP;
  gemm_proj_kernel<<<dim3(99, 6), 256, 0, stream>>>(Wproj, o_flat, bproj, xo,
                                                    cls_o);
}

// Round 2
// 2440.013 us; speedup vs baseline: 1.8409x; 1.8409x over previous
//
#include <hip/hip_runtime.h>

#define CDIM 768
#define BATCH 8
#define LDEPTH 8
#define HHEIGHT 14
#define WWIDTH 14
#define NSP 1568      // 8*14*14 spatial tokens (input / q)
#define NQTOK 1569    // +cls
#define NKSP 392      // 8*7*7 spatial tokens (k/v after pool)
#define NKTOK 393
#define NHEADS 12
#define HEADDIM 64
#define ATTN_SCALE 0.125f
#define LN_EPS 1e-6f
#define MTOK (BATCH * NQTOK)   // 12552 tokens for proj GEMM

// ---------------------------------------------------------------------------
// GEMM 1: Out[b][m][n] = sum_k W[m][k] * X[b][k][n] + bias[m]
// W: (768,768) row-major. X: (B,768,1568). Out: (B,768,1568).
// 128x128 tile, 8x8 microtile, Ktile=16.
// ---------------------------------------------------------------------------
__global__ __launch_bounds__(256) void gemm_wx_kernel(
    const float* __restrict__ W, const float* __restrict__ X,
    const float* __restrict__ bias, float* __restrict__ Out) {
  __shared__ float As[16][132];
  __shared__ float Bs[16][132];
  const int b = blockIdx.z;
  const int m0 = blockIdx.y * 128;
  const int n0 = blockIdx.x * 128;
  const int tid = threadIdx.x;
  const int tx = tid & 15, ty = tid >> 4;
  const float* Xb = X + (size_t)b * ((size_t)CDIM * NSP);

  float acc[8][8];
#pragma unroll
  for (int i = 0; i < 8; i++)
#pragma unroll
    for (int j = 0; j < 8; j++) acc[i][j] = 0.f;

  for (int k0 = 0; k0 < CDIM; k0 += 16) {
#pragma unroll
    for (int i = 0; i < 8; i++) {
      int idx = tid + i * 256;
      int r = idx >> 4, c = idx & 15;          // r: 0..127 (m), c: 0..15 (k)
      As[c][r] = W[(size_t)(m0 + r) * CDIM + k0 + c];
    }
#pragma unroll
    for (int i = 0; i < 8; i++) {
      int idx = tid + i * 256;
      int r = idx >> 7, c = idx & 127;         // r: 0..15 (k), c: 0..127 (n)
      int n = n0 + c;
      Bs[r][c] = (n < NSP) ? Xb[(size_t)(k0 + r) * NSP + n] : 0.f;
    }
    __syncthreads();
#pragma unroll
    for (int k = 0; k < 16; k++) {
      float av[8], bv[8];
      *(float4*)&av[0] = *(const float4*)&As[k][ty * 4];
      *(float4*)&av[4] = *(const float4*)&As[k][64 + ty * 4];
      *(float4*)&bv[0] = *(const float4*)&Bs[k][tx * 4];
      *(float4*)&bv[4] = *(const float4*)&Bs[k][64 + tx * 4];
#pragma unroll
      for (int i = 0; i < 8; i++)
#pragma unroll
        for (int j = 0; j < 8; j++) acc[i][j] = fmaf(av[i], bv[j], acc[i][j]);
    }
    __syncthreads();
  }

#pragma unroll
  for (int i = 0; i < 8; i++) {
    int mrow = m0 + (i >> 2) * 64 + ty * 4 + (i & 3);
    float bia = bias[mrow];
    float* orow = Out + ((size_t)b * CDIM + mrow) * (size_t)NSP;
#pragma unroll
    for (int jq = 0; jq < 2; jq++) {
      int n = n0 + jq * 64 + tx * 4;
      if (n < NSP) {
        float4 v;
        v.x = acc[i][jq * 4 + 0] + bia;
        v.y = acc[i][jq * 4 + 1] + bia;
        v.z = acc[i][jq * 4 + 2] + bia;
        v.w = acc[i][jq * 4 + 3] + bia;
        *(float4*)&orow[n] = v;
      }
    }
  }
}

// ---------------------------------------------------------------------------
// cls token linear: out[b][co] = dot(cls[b,:], W[co,:]) + bias[co]
// ---------------------------------------------------------------------------
__global__ __launch_bounds__(256) void cls_linear_kernel(
    const float* __restrict__ cls, const float* __restrict__ W,
    const float* __restrict__ bias, float* __restrict__ out) {
  __shared__ float xs[CDIM];
  const int b = blockIdx.x;
  for (int i = threadIdx.x; i < CDIM; i += 256) xs[i] = cls[b * CDIM + i];
  __syncthreads();
#pragma unroll
  for (int cc = 0; cc < 3; cc++) {
    int co = threadIdx.x + cc * 256;
    const float* wr = W + (size_t)co * CDIM;
    float sum = bias[co];
    for (int k = 0; k < CDIM; k += 4) {
      float4 wv = *(const float4*)&wr[k];
      float4 xv = *(const float4*)&xs[k];
      sum = fmaf(wv.x, xv.x, sum);
      sum = fmaf(wv.y, xv.y, sum);
      sum = fmaf(wv.z, xv.z, sum);
      sum = fmaf(wv.w, xv.w, sum);
    }
    out[b * CDIM + co] = sum;
  }
}

// ---------------------------------------------------------------------------
// Depthwise 3x3x3 conv. One block per (b,c) plane: stage the whole 1568-float
// input plane in LDS (coalesced), each thread computes output positions
// stride-256, writes coalesced to (B,C,npos).
// ---------------------------------------------------------------------------
__global__ __launch_bounds__(256) void dwconv_kernel(
    const float* __restrict__ X, const float* __restrict__ wconv,
    float* __restrict__ Out, int Lo, int Ho, int Wo, int sh, int sw) {
  __shared__ float xin[NSP];
  __shared__ float wsm[27];
  const int c = blockIdx.x % CDIM;
  const int b = blockIdx.x / CDIM;
  const float* xb = X + ((size_t)b * CDIM + c) * (size_t)NSP;
  for (int i = threadIdx.x; i < NSP; i += 256) xin[i] = xb[i];
  if (threadIdx.x < 27) wsm[threadIdx.x] = wconv[c * 27 + threadIdx.x];
  __syncthreads();
  const int npos = Lo * Ho * Wo;
  float* ob = Out + ((size_t)b * CDIM + c) * (size_t)npos;
  for (int pos = threadIdx.x; pos < npos; pos += 256) {
    int wo = pos % Wo;
    int ho = (pos / Wo) % Ho;
    int lo = pos / (Wo * Ho);
    int li0 = lo - 1, hi0 = ho * sh - 1, wi0 = wo * sw - 1;
    float sum = 0.f;
#pragma unroll
    for (int kd = 0; kd < 3; kd++) {
      int li = li0 + kd;
      if (li < 0 || li >= LDEPTH) continue;
#pragma unroll
      for (int kh = 0; kh < 3; kh++) {
        int hi = hi0 + kh;
        if (hi < 0 || hi >= HHEIGHT) continue;
#pragma unroll
        for (int kw = 0; kw < 3; kw++) {
          int wi = wi0 + kw;
          if (wi < 0 || wi >= WWIDTH) continue;
          sum = fmaf(xin[(li * HHEIGHT + hi) * WWIDTH + wi],
                     wsm[(kd * 3 + kh) * 3 + kw], sum);
        }
      }
    }
    ob[pos] = sum;
  }
}

// ---------------------------------------------------------------------------
// In-place LayerNorm over C. Grid (ceil(npos/64), B), block 256 = 4 waves.
// lane = position (coalesced), waves stride over channels, cross-wave
// reduction via LDS.
// ---------------------------------------------------------------------------
__global__ __launch_bounds__(256) void ln_kernel(
    float* __restrict__ Y, const float* __restrict__ ln_w,
    const float* __restrict__ ln_b, int npos) {
  const int b = blockIdx.y;
  const int lane = threadIdx.x & 63;
  const int wv = threadIdx.x >> 6;
  const int pos = blockIdx.x * 64 + lane;
  const bool act = pos < npos;
  float* Yb = Y + (size_t)b * CDIM * (size_t)npos;

  float s1 = 0.f, s2 = 0.f;
  for (int c = wv; c < CDIM; c += 4) {
    float v = act ? Yb[(size_t)c * npos + pos] : 0.f;
    s1 += v;
    s2 = fmaf(v, v, s2);
  }
  __shared__ float r1[4][64], r2[4][64];
  r1[wv][lane] = s1;
  r2[wv][lane] = s2;
  __syncthreads();
  float t1 = r1[0][lane] + r1[1][lane] + r1[2][lane] + r1[3][lane];
  float t2 = r2[0][lane] + r2[1][lane] + r2[2][lane] + r2[3][lane];
  float mean = t1 * (1.f / 768.f);
  float var = t2 * (1.f / 768.f) - mean * mean;
  float rstd = rsqrtf(var + LN_EPS);
  for (int c = wv; c < CDIM; c += 4) {
    if (act) {
      size_t idx = (size_t)c * npos + pos;
      float v = Yb[idx];
      Yb[idx] = (v - mean) * rstd * ln_w[c] + ln_b[c];
    }
  }
}

// ---------------------------------------------------------------------------
// Flash attention. Grid (7, 12, 8). One thread = one q token (online softmax).
// ---------------------------------------------------------------------------
__global__ __launch_bounds__(256) void attn_kernel(
    const float* __restrict__ qpool, const float* __restrict__ kpool,
    const float* __restrict__ vpool, const float* __restrict__ cls_q,
    const float* __restrict__ cls_k, const float* __restrict__ cls_v,
    float* __restrict__ o_flat) {
  __shared__ float lds_k[64 * 68];
  __shared__ float lds_v[64 * 68];
  const int b = blockIdx.z, h = blockIdx.y;
  const int nq = blockIdx.x * 256 + threadIdx.x;
  const bool active = nq < NQTOK;

  float q[64];
  if (active) {
    if (nq == 0) {
#pragma unroll
      for (int d = 0; d < 64; d++) q[d] = cls_q[b * CDIM + h * HEADDIM + d];
    } else {
#pragma unroll
      for (int d = 0; d < 64; d++)
        q[d] = qpool[(size_t)(b * CDIM + h * HEADDIM + d) * NSP + nq - 1];
    }
  } else {
#pragma unroll
    for (int d = 0; d < 64; d++) q[d] = 0.f;
  }

  float m = -1e30f, l = 0.f;
  float acc[64];
#pragma unroll
  for (int d = 0; d < 64; d++) acc[d] = 0.f;

  for (int kt = 0; kt < NKTOK; kt += 64) {
    const int count = min(64, NKTOK - kt);
    for (int i = threadIdx.x; i < 64 * 64; i += 256) {
      int t = i & 63, d = i >> 6;
      float kv = 0.f, vv = 0.f;
      int gt = kt + t;
      if (t < count) {
        if (gt == 0) {
          kv = cls_k[b * CDIM + h * HEADDIM + d];
          vv = cls_v[b * CDIM + h * HEADDIM + d];
        } else {
          size_t idx = (size_t)(b * CDIM + h * HEADDIM + d) * NKSP + gt - 1;
          kv = kpool[idx];
          vv = vpool[idx];
        }
      }
      lds_k[t * 68 + d] = kv;
      lds_v[t * 68 + d] = vv;
    }
    __syncthreads();
    if (active) {
      for (int cj = 0; cj < count; cj += 8) {
        int cn = min(8, count - cj);
        float s[8];
#pragma unroll
        for (int j = 0; j < 8; j++) {
          if (j < cn) {
            const float* kr = &lds_k[(cj + j) * 68];
            float sum = 0.f;
#pragma unroll
            for (int d4 = 0; d4 < 16; d4++) {
              float4 kv4 = *(const float4*)&kr[d4 * 4];
              sum = fmaf(q[d4 * 4 + 0], kv4.x, sum);
              sum = fmaf(q[d4 * 4 + 1], kv4.y, sum);
              sum = fmaf(q[d4 * 4 + 2], kv4.z, sum);
              sum = fmaf(q[d4 * 4 + 3], kv4.w, sum);
            }
            s[j] = sum * ATTN_SCALE;
          } else {
            s[j] = -1e30f;
          }
        }
        float cmax = s[0];
#pragma unroll
        for (int j = 1; j < 8; j++) cmax = fmaxf(cmax, s[j]);
        float mnew = fmaxf(m, cmax);
        float alpha = __expf(m - mnew);
        l *= alpha;
#pragma unroll
        for (int d = 0; d < 64; d++) acc[d] *= alpha;
#pragma unroll
        for (int j = 0; j < 8; j++) {
          if (j < cn) {
            float p = __expf(s[j] - mnew);
            l += p;
            const float* vr = &lds_v[(cj + j) * 68];
#pragma unroll
            for (int d = 0; d < 64; d++) acc[d] = fmaf(p, vr[d], acc[d]);
          }
        }
        m = mnew;
      }
    }
    __syncthreads();
  }

  if (active) {
    float inv = 1.f / l;
    float* op = &o_flat[((size_t)b * NQTOK + nq) * CDIM + h * HEADDIM];
#pragma unroll
    for (int d4 = 0; d4 < 16; d4++) {
      float4 o4;
      o4.x = acc[d4 * 4 + 0] * inv;
      o4.y = acc[d4 * 4 + 1] * inv;
      o4.z = acc[d4 * 4 + 2] * inv;
      o4.w = acc[d4 * 4 + 3] * inv;
      *(float4*)&op[d4 * 4] = o4;
    }
  }
}

// ---------------------------------------------------------------------------
// Projection GEMM: out[tok][co] = sum_k Wproj[co][k]*Tin[tok][k] + bias[co]
// ---------------------------------------------------------------------------
__global__ __launch_bounds__(256) void gemm_proj_kernel(
    const float* __restrict__ W, const float* __restrict__ Tin,
    const float* __restrict__ bias, float* __restrict__ xo,
    float* __restrict__ cls_o) {
  __shared__ float As[16][132];
  __shared__ float Bs[16][132];
  const int m0 = blockIdx.y * 128;   // c_out
  const int n0 = blockIdx.x * 128;   // token
  const int tid = threadIdx.x;
  const int tx = tid & 15, ty = tid >> 4;

  float acc[8][8];
#pragma unroll
  for (int i = 0; i < 8; i++)
#pragma unroll
    for (int j = 0; j < 8; j++) acc[i][j] = 0.f;

  for (int k0 = 0; k0 < CDIM; k0 += 16) {
#pragma unroll
    for (int i = 0; i < 8; i++) {
      int idx = tid + i * 256;
      int r = idx >> 4, c = idx & 15;
      As[c][r] = W[(size_t)(m0 + r) * CDIM + k0 + c];
    }
#pragma unroll
    for (int i = 0; i < 8; i++) {
      int idx = tid + i * 256;
      int tr = idx >> 4, c = idx & 15;
      int tok = n0 + tr;
      Bs[c][tr] = (tok < MTOK) ? Tin[(size_t)tok * CDIM + k0 + c] : 0.f;
    }
    __syncthreads();
#pragma unroll
    for (int k = 0; k < 16; k++) {
      float av[8], bv[8];
      *(float4*)&av[0] = *(const float4*)&As[k][ty * 4];
      *(float4*)&av[4] = *(const float4*)&As[k][64 + ty * 4];
      *(float4*)&bv[0] = *(const float4*)&Bs[k][tx * 4];
      *(float4*)&bv[4] = *(const float4*)&Bs[k][64 + tx * 4];
#pragma unroll
      for (int i = 0; i < 8; i++)
#pragma unroll
        for (int j = 0; j < 8; j++) acc[i][j] = fmaf(av[i], bv[j], acc[i][j]);
    }
    __syncthreads();
  }

#pragma unroll
  for (int i = 0; i < 8; i++) {
    int co = m0 + (i >> 2) * 64 + ty * 4 + (i & 3);
    float bia = bias[co];
#pragma unroll
    for (int j = 0; j < 8; j++) {
      int tok = n0 + (j >> 2) * 64 + tx * 4 + (j & 3);
      if (tok < MTOK) {
        int bb = tok / NQTOK;
        int nn = tok % NQTOK;
        float v = acc[i][j] + bia;
        if (nn == 0)
          cls_o[bb * CDIM + co] = v;
        else
          xo[((size_t)bb * CDIM + co) * (size_t)NSP + nn - 1] = v;
      }
    }
  }
}

// ---------------------------------------------------------------------------
extern "C" void kernel_launch(void* const* d_in, const int* in_sizes, int n_in,
                              void* d_out, int out_size, void* d_ws, size_t ws_size,
                              hipStream_t stream) {
  const float* x      = (const float*)d_in[0];
  const float* cls    = (const float*)d_in[1];
  const float* Wq     = (const float*)d_in[2];
  const float* bq     = (const float*)d_in[3];
  const float* Wk     = (const float*)d_in[4];
  const float* bk     = (const float*)d_in[5];
  const float* Wv     = (const float*)d_in[6];
  const float* bv     = (const float*)d_in[7];
  const float* conv_q = (const float*)d_in[8];
  const float* conv_k = (const float*)d_in[9];
  const float* conv_v = (const float*)d_in[10];
  const float* lnq_w  = (const float*)d_in[11];
  const float* lnq_b  = (const float*)d_in[12];
  const float* lnk_w  = (const float*)d_in[13];
  const float* lnk_b  = (const float*)d_in[14];
  const float* lnv_w  = (const float*)d_in[15];
  const float* lnv_b  = (const float*)d_in[16];
  const float* Wproj  = (const float*)d_in[17];
  const float* bproj  = (const float*)d_in[18];

  // Workspace layout (floats). Total = 43,370,496 floats = 173.5 MB.
  float* ws = (float*)d_ws;
  const size_t SZ_LIN = (size_t)BATCH * CDIM * NSP;     // 9,633,792
  const size_t SZ_KV  = (size_t)BATCH * CDIM * NKSP;    // 2,408,448
  const size_t SZ_CLS = (size_t)BATCH * CDIM;           // 6,144
  size_t off = 0;
  float* q_lin  = ws + off; off += SZ_LIN;
  float* q_pool = ws + off; off += SZ_LIN;
  float* k_pool = ws + off; off += SZ_KV;
  float* v_pool = ws + off; off += SZ_KV;
  float* clsq   = ws + off; off += SZ_CLS;
  float* clsk   = ws + off; off += SZ_CLS;
  float* clsv   = ws + off; off += SZ_CLS;
  float* k_lin  = ws + off; off += SZ_LIN;
  float* v_lin  = ws + off; off += SZ_LIN;
  float* o_flat = k_lin;  // aliases dead k_lin/v_lin region during attention

  dim3 gw(13, 6, BATCH);   // ceil(1568/128)=13, 768/128=6
  gemm_wx_kernel<<<gw, 256, 0, stream>>>(Wq, x, bq, q_lin);
  gemm_wx_kernel<<<gw, 256, 0, stream>>>(Wk, x, bk, k_lin);
  gemm_wx_kernel<<<gw, 256, 0, stream>>>(Wv, x, bv, v_lin);

  cls_linear_kernel<<<BATCH, 256, 0, stream>>>(cls, Wq, bq, clsq);
  cls_linear_kernel<<<BATCH, 256, 0, stream>>>(cls, Wk, bk, clsk);
  cls_linear_kernel<<<BATCH, 256, 0, stream>>>(cls, Wv, bv, clsv);

  dwconv_kernel<<<BATCH * CDIM, 256, 0, stream>>>(q_lin, conv_q, q_pool,
                                                  8, 14, 14, 1, 1);
  dwconv_kernel<<<BATCH * CDIM, 256, 0, stream>>>(k_lin, conv_k, k_pool,
                                                  8, 7, 7, 2, 2);
  dwconv_kernel<<<BATCH * CDIM, 256, 0, stream>>>(v_lin, conv_v, v_pool,
                                                  8, 7, 7, 2, 2);

  ln_kernel<<<dim3(25, BATCH), 256, 0, stream>>>(q_pool, lnq_w, lnq_b, NSP);
  ln_kernel<<<dim3(7, BATCH), 256, 0, stream>>>(k_pool, lnk_w, lnk_b, NKSP);
  ln_kernel<<<dim3(7, BATCH), 256, 0, stream>>>(v_pool, lnv_w, lnv_b, NKSP);

  attn_kernel<<<dim3(7, NHEADS, BATCH), 256, 0, stream>>>(
      q_pool, k_pool, v_pool, clsq, clsk, clsv, o_flat);

  float* xo = (float*)d_out;
  float* cls_o = (float*)d_out + (size_t)BATCH * CDIM * NSP;
  gemm_proj_kernel<<<dim3(99, 6), 256, 0, stream>>>(Wproj, o_flat, bproj, xo,
                                                    cls_o);
}

// Round 3
// 1085.288 us; speedup vs baseline: 4.1389x; 2.2483x over previous
//
#include <hip/hip_runtime.h>

#define CDIM 768
#define BATCH 8
#define LDEPTH 8
#define HHEIGHT 14
#define WWIDTH 14
#define NSP 1568      // 8*14*14 spatial tokens (input / q)
#define NQTOK 1569    // +cls
#define NKSP 392      // 8*7*7 spatial tokens (k/v after pool)
#define NKTOK 393
#define NHEADS 12
#define HEADDIM 64
#define ATTN_SCALE 0.125f
#define LN_EPS 1e-6f
#define MTOK (BATCH * NQTOK)   // 12552 tokens for proj GEMM
#define NPAD_X 1664            // Xt padded rows per batch (13 tiles * 128)
#define NPAD_TOK 12672         // o16 padded tokens (99 tiles * 128)
#define WELEM (CDIM * CDIM)    // 589824

typedef _Float16 f16;
typedef _Float16 f16x8_t __attribute__((ext_vector_type(8)));
typedef _Float16 f16x4_t __attribute__((ext_vector_type(4)));
typedef float f32x4_t __attribute__((ext_vector_type(4)));

// ---------------------------------------------------------------------------
// fp32 -> fp16 convert (for weight matrices)
// ---------------------------------------------------------------------------
__global__ __launch_bounds__(256) void convert_f16_kernel(
    const float* __restrict__ src, f16* __restrict__ dst, int n) {
  int i = (blockIdx.x * 256 + threadIdx.x) * 4;
  if (i < n) {
    float4 v = *(const float4*)&src[i];
    f16x4_t h = {(f16)v.x, (f16)v.y, (f16)v.z, (f16)v.w};
    *(f16x4_t*)&dst[i] = h;
  }
}

// ---------------------------------------------------------------------------
// Transpose+convert X: (B,768,1568) f32 -> Xt (B,1664,768) f16, pad rows = 0.
// ---------------------------------------------------------------------------
__global__ __launch_bounds__(256) void transpose_x_kernel(
    const float* __restrict__ X, f16* __restrict__ Xt) {
  __shared__ float t[32][33];
  const int b = blockIdx.z;
  const int k0 = blockIdx.y * 32;   // 768/32 = 24
  const int n0 = blockIdx.x * 32;   // 1664/32 = 52
  const int tx = threadIdx.x & 31, ty = threadIdx.x >> 5;  // ty 0..7
#pragma unroll
  for (int i = 0; i < 4; i++) {
    int k = k0 + ty + i * 8;
    int n = n0 + tx;
    t[ty + i * 8][tx] = (n < NSP) ? X[((size_t)b * CDIM + k) * NSP + n] : 0.f;
  }
  __syncthreads();
#pragma unroll
  for (int i = 0; i < 4; i++) {
    int n = n0 + ty + i * 8;
    Xt[((size_t)b * NPAD_X + n) * CDIM + k0 + tx] = (f16)t[tx][ty + i * 8];
  }
}

// ---------------------------------------------------------------------------
// Fused QKV MFMA GEMM: Out[mat][b][m][n] = sum_k W16[mat][m][k]*Xt[b][n][k]+bias
// Grid (13, 18, 8): blockIdx.y -> (mat = y/6, m-tile = y%6). 128x128 tile,
// BK=32, 4 waves (2x2), wave = 64x64 = 4x4 frags of 16x16x32 f16 MFMA.
// ---------------------------------------------------------------------------
__global__ __launch_bounds__(256) void gemm_qkv_f16_kernel(
    const f16* __restrict__ W16, const f16* __restrict__ Xt,
    const float* __restrict__ bq, const float* __restrict__ bk,
    const float* __restrict__ bv, float* __restrict__ OutBase) {
  __shared__ __align__(16) f16 Asm[128 * 32];
  __shared__ __align__(16) f16 Bsm[128 * 32];

  const int b = blockIdx.z;
  const int mat = blockIdx.y / 6;
  const int m0 = (blockIdx.y % 6) * 128;
  const int n0 = blockIdx.x * 128;
  const int tid = threadIdx.x;
  const int lane = tid & 63;
  const int w = tid >> 6;
  const int wr = w >> 1, wc = w & 1;
  const int l15 = lane & 15, l4 = lane >> 4;

  const f16* A16 = W16 + (size_t)mat * WELEM;
  const float* bias = (mat == 0) ? bq : (mat == 1) ? bk : bv;
  float* Out = OutBase + (size_t)mat * ((size_t)BATCH * CDIM * NSP);

  // staging: chunk0 rows tid>>2 (0..63), chunk1 rows +64; 8 fp16 per thread each
  const int r0 = tid >> 2;
  const int kq = (tid & 3) * 8;
  const f16* Ag0 = A16 + (size_t)(m0 + r0) * CDIM + kq;
  const f16* Ag1 = Ag0 + 64 * CDIM;
  const f16* Bg0 = Xt + ((size_t)b * NPAD_X + n0 + r0) * CDIM + kq;
  const f16* Bg1 = Bg0 + 64 * CDIM;

  f32x4_t acc[4][4];
#pragma unroll
  for (int i = 0; i < 4; i++)
#pragma unroll
    for (int j = 0; j < 4; j++) acc[i][j] = (f32x4_t){0.f, 0.f, 0.f, 0.f};

  uint4 ra0 = *(const uint4*)Ag0;
  uint4 ra1 = *(const uint4*)Ag1;
  uint4 rb0 = *(const uint4*)Bg0;
  uint4 rb1 = *(const uint4*)Bg1;

  for (int k0 = 0; k0 < CDIM; k0 += 32) {
    __syncthreads();
    *(uint4*)(Asm + tid * 8) = ra0;
    *(uint4*)(Asm + 2048 + tid * 8) = ra1;
    *(uint4*)(Bsm + tid * 8) = rb0;
    *(uint4*)(Bsm + 2048 + tid * 8) = rb1;
    if (k0 + 32 < CDIM) {
      ra0 = *(const uint4*)(Ag0 + k0 + 32);
      ra1 = *(const uint4*)(Ag1 + k0 + 32);
      rb0 = *(const uint4*)(Bg0 + k0 + 32);
      rb1 = *(const uint4*)(Bg1 + k0 + 32);
    }
    __syncthreads();
    f16x8_t af[4], bf[4];
#pragma unroll
    for (int mi = 0; mi < 4; mi++)
      af[mi] = *(const f16x8_t*)(Asm + (wr * 64 + mi * 16 + l15) * 32 + l4 * 8);
#pragma unroll
    for (int ni = 0; ni < 4; ni++)
      bf[ni] = *(const f16x8_t*)(Bsm + (wc * 64 + ni * 16 + l15) * 32 + l4 * 8);
#pragma unroll
    for (int mi = 0; mi < 4; mi++)
#pragma unroll
      for (int ni = 0; ni < 4; ni++)
        acc[mi][ni] = __builtin_amdgcn_mfma_f32_16x16x32_f16(
            af[mi], bf[ni], acc[mi][ni], 0, 0, 0);
  }

#pragma unroll
  for (int mi = 0; mi < 4; mi++) {
    const int mbase = m0 + wr * 64 + mi * 16 + l4 * 4;
#pragma unroll
    for (int ni = 0; ni < 4; ni++) {
      const int n = n0 + wc * 64 + ni * 16 + l15;
      if (n < NSP) {
#pragma unroll
        for (int r = 0; r < 4; r++) {
          Out[((size_t)b * CDIM + mbase + r) * NSP + n] =
              acc[mi][ni][r] + bias[mbase + r];
        }
      }
    }
  }
}

// ---------------------------------------------------------------------------
// Projection MFMA GEMM: out[tok][co] = sum_k Wp16[co][k]*o16[tok][k] + bias
// o16: (NPAD_TOK, 768) f16 token-major. Scatter to xo/cls_o (fp32).
// ---------------------------------------------------------------------------
__global__ __launch_bounds__(256) void gemm_proj_f16_kernel(
    const f16* __restrict__ Wp16, const f16* __restrict__ o16,
    const float* __restrict__ bias, float* __restrict__ xo,
    float* __restrict__ cls_o) {
  __shared__ __align__(16) f16 Asm[128 * 32];
  __shared__ __align__(16) f16 Bsm[128 * 32];

  const int m0 = blockIdx.y * 128;   // c_out
  const int n0 = blockIdx.x * 128;   // token
  const int tid = threadIdx.x;
  const int lane = tid & 63;
  const int w = tid >> 6;
  const int wr = w >> 1, wc = w & 1;
  const int l15 = lane & 15, l4 = lane >> 4;

  const int r0 = tid >> 2;
  const int kq = (tid & 3) * 8;
  const f16* Ag0 = Wp16 + (size_t)(m0 + r0) * CDIM + kq;
  const f16* Ag1 = Ag0 + 64 * CDIM;
  const f16* Bg0 = o16 + (size_t)(n0 + r0) * CDIM + kq;
  const f16* Bg1 = Bg0 + 64 * CDIM;

  f32x4_t acc[4][4];
#pragma unroll
  for (int i = 0; i < 4; i++)
#pragma unroll
    for (int j = 0; j < 4; j++) acc[i][j] = (f32x4_t){0.f, 0.f, 0.f, 0.f};

  uint4 ra0 = *(const uint4*)Ag0;
  uint4 ra1 = *(const uint4*)Ag1;
  uint4 rb0 = *(const uint4*)Bg0;
  uint4 rb1 = *(const uint4*)Bg1;

  for (int k0 = 0; k0 < CDIM; k0 += 32) {
    __syncthreads();
    *(uint4*)(Asm + tid * 8) = ra0;
    *(uint4*)(Asm + 2048 + tid * 8) = ra1;
    *(uint4*)(Bsm + tid * 8) = rb0;
    *(uint4*)(Bsm + 2048 + tid * 8) = rb1;
    if (k0 + 32 < CDIM) {
      ra0 = *(const uint4*)(Ag0 + k0 + 32);
      ra1 = *(const uint4*)(Ag1 + k0 + 32);
      rb0 = *(const uint4*)(Bg0 + k0 + 32);
      rb1 = *(const uint4*)(Bg1 + k0 + 32);
    }
    __syncthreads();
    f16x8_t af[4], bf[4];
#pragma unroll
    for (int mi = 0; mi < 4; mi++)
      af[mi] = *(const f16x8_t*)(Asm + (wr * 64 + mi * 16 + l15) * 32 + l4 * 8);
#pragma unroll
    for (int ni = 0; ni < 4; ni++)
      bf[ni] = *(const f16x8_t*)(Bsm + (wc * 64 + ni * 16 + l15) * 32 + l4 * 8);
#pragma unroll
    for (int mi = 0; mi < 4; mi++)
#pragma unroll
      for (int ni = 0; ni < 4; ni++)
        acc[mi][ni] = __builtin_amdgcn_mfma_f32_16x16x32_f16(
            af[mi], bf[ni], acc[mi][ni], 0, 0, 0);
  }

#pragma unroll
  for (int mi = 0; mi < 4; mi++) {
    const int mbase = m0 + wr * 64 + mi * 16 + l4 * 4;
#pragma unroll
    for (int ni = 0; ni < 4; ni++) {
      const int tok = n0 + wc * 64 + ni * 16 + l15;
      if (tok < MTOK) {
        const int bb = tok / NQTOK;
        const int nn = tok % NQTOK;
#pragma unroll
        for (int r = 0; r < 4; r++) {
          float v = acc[mi][ni][r] + bias[mbase + r];
          if (nn == 0)
            cls_o[bb * CDIM + mbase + r] = v;
          else
            xo[((size_t)bb * CDIM + mbase + r) * (size_t)NSP + nn - 1] = v;
        }
      }
    }
  }
}

// ---------------------------------------------------------------------------
// cls token linear (fp32): out[b][co] = dot(cls[b,:], W[co,:]) + bias[co]
// ---------------------------------------------------------------------------
__global__ __launch_bounds__(256) void cls_linear_kernel(
    const float* __restrict__ cls, const float* __restrict__ W,
    const float* __restrict__ bias, float* __restrict__ out) {
  __shared__ float xs[CDIM];
  const int b = blockIdx.x;
  for (int i = threadIdx.x; i < CDIM; i += 256) xs[i] = cls[b * CDIM + i];
  __syncthreads();
#pragma unroll
  for (int cc = 0; cc < 3; cc++) {
    int co = threadIdx.x + cc * 256;
    const float* wr = W + (size_t)co * CDIM;
    float sum = bias[co];
    for (int k = 0; k < CDIM; k += 4) {
      float4 wv = *(const float4*)&wr[k];
      float4 xv = *(const float4*)&xs[k];
      sum = fmaf(wv.x, xv.x, sum);
      sum = fmaf(wv.y, xv.y, sum);
      sum = fmaf(wv.z, xv.z, sum);
      sum = fmaf(wv.w, xv.w, sum);
    }
    out[b * CDIM + co] = sum;
  }
}

// ---------------------------------------------------------------------------
// Depthwise 3x3x3 conv. One block per (b,c) plane, LDS-staged input plane.
// ---------------------------------------------------------------------------
__global__ __launch_bounds__(256) void dwconv_kernel(
    const float* __restrict__ X, const float* __restrict__ wconv,
    float* __restrict__ Out, int Lo, int Ho, int Wo, int sh, int sw) {
  __shared__ float xin[NSP];
  __shared__ float wsm[27];
  const int c = blockIdx.x % CDIM;
  const int b = blockIdx.x / CDIM;
  const float* xb = X + ((size_t)b * CDIM + c) * (size_t)NSP;
  for (int i = threadIdx.x; i < NSP; i += 256) xin[i] = xb[i];
  if (threadIdx.x < 27) wsm[threadIdx.x] = wconv[c * 27 + threadIdx.x];
  __syncthreads();
  const int npos = Lo * Ho * Wo;
  float* ob = Out + ((size_t)b * CDIM + c) * (size_t)npos;
  for (int pos = threadIdx.x; pos < npos; pos += 256) {
    int wo = pos % Wo;
    int ho = (pos / Wo) % Ho;
    int lo = pos / (Wo * Ho);
    int li0 = lo - 1, hi0 = ho * sh - 1, wi0 = wo * sw - 1;
    float sum = 0.f;
#pragma unroll
    for (int kd = 0; kd < 3; kd++) {
      int li = li0 + kd;
      if (li < 0 || li >= LDEPTH) continue;
#pragma unroll
      for (int kh = 0; kh < 3; kh++) {
        int hi = hi0 + kh;
        if (hi < 0 || hi >= HHEIGHT) continue;
#pragma unroll
        for (int kw = 0; kw < 3; kw++) {
          int wi = wi0 + kw;
          if (wi < 0 || wi >= WWIDTH) continue;
          sum = fmaf(xin[(li * HHEIGHT + hi) * WWIDTH + wi],
                     wsm[(kd * 3 + kh) * 3 + kw], sum);
        }
      }
    }
    ob[pos] = sum;
  }
}

// ---------------------------------------------------------------------------
// In-place LayerNorm over C. Grid (ceil(npos/64), B), block 256 = 4 waves.
// ---------------------------------------------------------------------------
__global__ __launch_bounds__(256) void ln_kernel(
    float* __restrict__ Y, const float* __restrict__ ln_w,
    const float* __restrict__ ln_b, int npos) {
  const int b = blockIdx.y;
  const int lane = threadIdx.x & 63;
  const int wv = threadIdx.x >> 6;
  const int pos = blockIdx.x * 64 + lane;
  const bool act = pos < npos;
  float* Yb = Y + (size_t)b * CDIM * (size_t)npos;

  float s1 = 0.f, s2 = 0.f;
  for (int c = wv; c < CDIM; c += 4) {
    float v = act ? Yb[(size_t)c * npos + pos] : 0.f;
    s1 += v;
    s2 = fmaf(v, v, s2);
  }
  __shared__ float r1[4][64], r2[4][64];
  r1[wv][lane] = s1;
  r2[wv][lane] = s2;
  __syncthreads();
  float t1 = r1[0][lane] + r1[1][lane] + r1[2][lane] + r1[3][lane];
  float t2 = r2[0][lane] + r2[1][lane] + r2[2][lane] + r2[3][lane];
  float mean = t1 * (1.f / 768.f);
  float var = t2 * (1.f / 768.f) - mean * mean;
  float rstd = rsqrtf(var + LN_EPS);
  for (int c = wv; c < CDIM; c += 4) {
    if (act) {
      size_t idx = (size_t)c * npos + pos;
      float v = Yb[idx];
      Yb[idx] = (v - mean) * rstd * ln_w[c] + ln_b[c];
    }
  }
}

// ---------------------------------------------------------------------------
// Flash attention (fp32 compute), writes o16 (f16, token-major).
// ---------------------------------------------------------------------------
__global__ __launch_bounds__(256) void attn_kernel(
    const float* __restrict__ qpool, const float* __restrict__ kpool,
    const float* __restrict__ vpool, const float* __restrict__ cls_q,
    const float* __restrict__ cls_k, const float* __restrict__ cls_v,
    f16* __restrict__ o16) {
  __shared__ float lds_k[64 * 68];
  __shared__ float lds_v[64 * 68];
  const int b = blockIdx.z, h = blockIdx.y;
  const int nq = blockIdx.x * 256 + threadIdx.x;
  const bool active = nq < NQTOK;

  float q[64];
  if (active) {
    if (nq == 0) {
#pragma unroll
      for (int d = 0; d < 64; d++) q[d] = cls_q[b * CDIM + h * HEADDIM + d];
    } else {
#pragma unroll
      for (int d = 0; d < 64; d++)
        q[d] = qpool[(size_t)(b * CDIM + h * HEADDIM + d) * NSP + nq - 1];
    }
  } else {
#pragma unroll
    for (int d = 0; d < 64; d++) q[d] = 0.f;
  }

  float m = -1e30f, l = 0.f;
  float acc[64];
#pragma unroll
  for (int d = 0; d < 64; d++) acc[d] = 0.f;

  for (int kt = 0; kt < NKTOK; kt += 64) {
    const int count = min(64, NKTOK - kt);
    for (int i = threadIdx.x; i < 64 * 64; i += 256) {
      int t = i & 63, d = i >> 6;
      float kv = 0.f, vv = 0.f;
      int gt = kt + t;
      if (t < count) {
        if (gt == 0) {
          kv = cls_k[b * CDIM + h * HEADDIM + d];
          vv = cls_v[b * CDIM + h * HEADDIM + d];
        } else {
          size_t idx = (size_t)(b * CDIM + h * HEADDIM + d) * NKSP + gt - 1;
          kv = kpool[idx];
          vv = vpool[idx];
        }
      }
      lds_k[t * 68 + d] = kv;
      lds_v[t * 68 + d] = vv;
    }
    __syncthreads();
    if (active) {
      for (int cj = 0; cj < count; cj += 8) {
        int cn = min(8, count - cj);
        float s[8];
#pragma unroll
        for (int j = 0; j < 8; j++) {
          if (j < cn) {
            const float* kr = &lds_k[(cj + j) * 68];
            float sum = 0.f;
#pragma unroll
            for (int d4 = 0; d4 < 16; d4++) {
              float4 kv4 = *(const float4*)&kr[d4 * 4];
              sum = fmaf(q[d4 * 4 + 0], kv4.x, sum);
              sum = fmaf(q[d4 * 4 + 1], kv4.y, sum);
              sum = fmaf(q[d4 * 4 + 2], kv4.z, sum);
              sum = fmaf(q[d4 * 4 + 3], kv4.w, sum);
            }
            s[j] = sum * ATTN_SCALE;
          } else {
            s[j] = -1e30f;
          }
        }
        float cmax = s[0];
#pragma unroll
        for (int j = 1; j < 8; j++) cmax = fmaxf(cmax, s[j]);
        float mnew = fmaxf(m, cmax);
        float alpha = __expf(m - mnew);
        l *= alpha;
#pragma unroll
        for (int d = 0; d < 64; d++) acc[d] *= alpha;
#pragma unroll
        for (int j = 0; j < 8; j++) {
          if (j < cn) {
            float p = __expf(s[j] - mnew);
            l += p;
            const float* vr = &lds_v[(cj + j) * 68];
#pragma unroll
            for (int d = 0; d < 64; d++) acc[d] = fmaf(p, vr[d], acc[d]);
          }
        }
        m = mnew;
      }
    }
    __syncthreads();
  }

  if (active) {
    float inv = 1.f / l;
    f16* op = &o16[((size_t)b * NQTOK + nq) * CDIM + h * HEADDIM];
#pragma unroll
    for (int d4 = 0; d4 < 16; d4++) {
      f16x4_t h4 = {(f16)(acc[d4 * 4 + 0] * inv), (f16)(acc[d4 * 4 + 1] * inv),
                    (f16)(acc[d4 * 4 + 2] * inv), (f16)(acc[d4 * 4 + 3] * inv)};
      *(f16x4_t*)&op[d4 * 4] = h4;
    }
  }
}

// ---------------------------------------------------------------------------
extern "C" void kernel_launch(void* const* d_in, const int* in_sizes, int n_in,
                              void* d_out, int out_size, void* d_ws, size_t ws_size,
                              hipStream_t stream) {
  const float* x      = (const float*)d_in[0];
  const float* cls    = (const float*)d_in[1];
  const float* Wq     = (const float*)d_in[2];
  const float* bq     = (const float*)d_in[3];
  const float* Wk     = (const float*)d_in[4];
  const float* bk     = (const float*)d_in[5];
  const float* Wv     = (const float*)d_in[6];
  const float* bv     = (const float*)d_in[7];
  const float* conv_q = (const float*)d_in[8];
  const float* conv_k = (const float*)d_in[9];
  const float* conv_v = (const float*)d_in[10];
  const float* lnq_w  = (const float*)d_in[11];
  const float* lnq_b  = (const float*)d_in[12];
  const float* lnk_w  = (const float*)d_in[13];
  const float* lnk_b  = (const float*)d_in[14];
  const float* lnv_w  = (const float*)d_in[15];
  const float* lnv_b  = (const float*)d_in[16];
  const float* Wproj  = (const float*)d_in[17];
  const float* bproj  = (const float*)d_in[18];

  // Workspace layout (bytes). Total = 160,112,640 B ≈ 160.1 MB.
  char* wsb = (char*)d_ws;
  f16*   Xt     = (f16*)(wsb + 0);            // 8*1664*768*2 = 20,447,232 B
  f16*   W16    = (f16*)(wsb + 20447232);     // 4*589824*2  =  4,718,592 B
  float* q_lin  = (float*)(wsb + 25165824);   // 38,535,168 B
  float* k_lin  = (float*)(wsb + 63700992);   // 38,535,168 B
  float* v_lin  = (float*)(wsb + 102236160);  // 38,535,168 B
  float* k_pool = (float*)(wsb + 140771328);  //  9,633,792 B
  float* v_pool = (float*)(wsb + 150405120);  //  9,633,792 B
  float* clsq   = (float*)(wsb + 160038912);  //     24,576 B
  float* clsk   = (float*)(wsb + 160063488);
  float* clsv   = (float*)(wsb + 160088064);
  float* q_pool = k_lin;   // alias: k_lin dead after dwconv-k
  f16*   o16    = Xt;      // alias: Xt dead after QKV GEMMs (12672*768 fits)

  f16* W16q = W16;
  f16* W16k = W16 + (size_t)WELEM;
  f16* W16v = W16 + (size_t)2 * WELEM;
  f16* W16p = W16 + (size_t)3 * WELEM;

  // 1. convert weights to fp16
  convert_f16_kernel<<<576, 256, 0, stream>>>(Wq, W16q, WELEM);
  convert_f16_kernel<<<576, 256, 0, stream>>>(Wk, W16k, WELEM);
  convert_f16_kernel<<<576, 256, 0, stream>>>(Wv, W16v, WELEM);
  convert_f16_kernel<<<576, 256, 0, stream>>>(Wproj, W16p, WELEM);

  // 2. transpose+convert X -> Xt (k-major, padded)
  transpose_x_kernel<<<dim3(52, 24, BATCH), 256, 0, stream>>>(x, Xt);

  // 3. fused QKV MFMA GEMM (writes q_lin, k_lin, v_lin contiguously)
  gemm_qkv_f16_kernel<<<dim3(13, 18, BATCH), 256, 0, stream>>>(
      W16, Xt, bq, bk, bv, q_lin);

  // 4. cls token linears (fp32)
  cls_linear_kernel<<<BATCH, 256, 0, stream>>>(cls, Wq, bq, clsq);
  cls_linear_kernel<<<BATCH, 256, 0, stream>>>(cls, Wk, bk, clsk);
  cls_linear_kernel<<<BATCH, 256, 0, stream>>>(cls, Wv, bv, clsv);

  // 5. depthwise convs (k first, v, then q: q_pool aliases k_lin)
  dwconv_kernel<<<BATCH * CDIM, 256, 0, stream>>>(k_lin, conv_k, k_pool,
                                                  8, 7, 7, 2, 2);
  dwconv_kernel<<<BATCH * CDIM, 256, 0, stream>>>(v_lin, conv_v, v_pool,
                                                  8, 7, 7, 2, 2);
  dwconv_kernel<<<BATCH * CDIM, 256, 0, stream>>>(q_lin, conv_q, q_pool,
                                                  8, 14, 14, 1, 1);

  // 6. layernorms
  ln_kernel<<<dim3(25, BATCH), 256, 0, stream>>>(q_pool, lnq_w, lnq_b, NSP);
  ln_kernel<<<dim3(7, BATCH), 256, 0, stream>>>(k_pool, lnk_w, lnk_b, NKSP);
  ln_kernel<<<dim3(7, BATCH), 256, 0, stream>>>(v_pool, lnv_w, lnv_b, NKSP);

  // 7. attention -> o16 (f16 token-major, in dead Xt region)
  attn_kernel<<<dim3(7, NHEADS, BATCH), 256, 0, stream>>>(
      q_pool, k_pool, v_pool, clsq, clsk, clsv, o16);

  // 8. projection MFMA GEMM -> d_out
  float* xo = (float*)d_out;
  float* cls_o = (float*)d_out + (size_t)BATCH * CDIM * NSP;
  gemm_proj_f16_kernel<<<dim3(99, 6), 256, 0, stream>>>(W16p, o16, bproj, xo,
                                                        cls_o);
}

// Round 4
// 818.328 us; speedup vs baseline: 5.4892x; 1.3262x over previous
//
#include <hip/hip_runtime.h>

#define CDIM 768
#define BATCH 8
#define LDEPTH 8
#define HHEIGHT 14
#define WWIDTH 14
#define NSP 1568      // 8*14*14 spatial tokens (input / q)
#define NQTOK 1569    // +cls
#define NKSP 392      // 8*7*7 spatial tokens (k/v after pool)
#define NKTOK 393
#define NHEADS 12
#define HEADDIM 64
#define ATTN_SCALE 0.125f
#define LN_EPS 1e-6f
#define MTOK (BATCH * NQTOK)   // 12552 tokens for proj GEMM
#define NPAD_X 1664            // Xt padded rows per batch (13 tiles * 128)
#define NPAD_TOK 12672         // o16 padded tokens (99 tiles * 128)
#define WELEM (CDIM * CDIM)    // 589824
#define TQP 1664               // padded q tokens per (b,h)  (13*128)
#define TKP 448                // padded kv tokens per (b,h) (7*64)

typedef _Float16 f16;
typedef _Float16 f16x8_t __attribute__((ext_vector_type(8)));
typedef _Float16 f16x4_t __attribute__((ext_vector_type(4)));
typedef float f32x4_t __attribute__((ext_vector_type(4)));

// ---------------------------------------------------------------------------
// fp32 -> fp16 convert (for weight matrices)
// ---------------------------------------------------------------------------
__global__ __launch_bounds__(256) void convert_f16_kernel(
    const float* __restrict__ src, f16* __restrict__ dst, int n) {
  int i = (blockIdx.x * 256 + threadIdx.x) * 4;
  if (i < n) {
    float4 v = *(const float4*)&src[i];
    f16x4_t h = {(f16)v.x, (f16)v.y, (f16)v.z, (f16)v.w};
    *(f16x4_t*)&dst[i] = h;
  }
}

// ---------------------------------------------------------------------------
// Transpose+convert X: (B,768,1568) f32 -> Xt (B,1664,768) f16, pad rows = 0.
// ---------------------------------------------------------------------------
__global__ __launch_bounds__(256) void transpose_x_kernel(
    const float* __restrict__ X, f16* __restrict__ Xt) {
  __shared__ float t[32][33];
  const int b = blockIdx.z;
  const int k0 = blockIdx.y * 32;
  const int n0 = blockIdx.x * 32;
  const int tx = threadIdx.x & 31, ty = threadIdx.x >> 5;
#pragma unroll
  for (int i = 0; i < 4; i++) {
    int k = k0 + ty + i * 8;
    int n = n0 + tx;
    t[ty + i * 8][tx] = (n < NSP) ? X[((size_t)b * CDIM + k) * NSP + n] : 0.f;
  }
  __syncthreads();
#pragma unroll
  for (int i = 0; i < 4; i++) {
    int n = n0 + ty + i * 8;
    Xt[((size_t)b * NPAD_X + n) * CDIM + k0 + tx] = (f16)t[tx][ty + i * 8];
  }
}

// ---------------------------------------------------------------------------
// Fused QKV MFMA GEMM (unchanged from round 3).
// ---------------------------------------------------------------------------
__global__ __launch_bounds__(256) void gemm_qkv_f16_kernel(
    const f16* __restrict__ W16, const f16* __restrict__ Xt,
    const float* __restrict__ bq, const float* __restrict__ bk,
    const float* __restrict__ bv, float* __restrict__ OutBase) {
  __shared__ __align__(16) f16 Asm[128 * 32];
  __shared__ __align__(16) f16 Bsm[128 * 32];

  const int b = blockIdx.z;
  const int mat = blockIdx.y / 6;
  const int m0 = (blockIdx.y % 6) * 128;
  const int n0 = blockIdx.x * 128;
  const int tid = threadIdx.x;
  const int lane = tid & 63;
  const int w = tid >> 6;
  const int wr = w >> 1, wc = w & 1;
  const int l15 = lane & 15, l4 = lane >> 4;

  const f16* A16 = W16 + (size_t)mat * WELEM;
  const float* bias = (mat == 0) ? bq : (mat == 1) ? bk : bv;
  float* Out = OutBase + (size_t)mat * ((size_t)BATCH * CDIM * NSP);

  const int r0 = tid >> 2;
  const int kq = (tid & 3) * 8;
  const f16* Ag0 = A16 + (size_t)(m0 + r0) * CDIM + kq;
  const f16* Ag1 = Ag0 + 64 * CDIM;
  const f16* Bg0 = Xt + ((size_t)b * NPAD_X + n0 + r0) * CDIM + kq;
  const f16* Bg1 = Bg0 + 64 * CDIM;

  f32x4_t acc[4][4];
#pragma unroll
  for (int i = 0; i < 4; i++)
#pragma unroll
    for (int j = 0; j < 4; j++) acc[i][j] = (f32x4_t){0.f, 0.f, 0.f, 0.f};

  uint4 ra0 = *(const uint4*)Ag0;
  uint4 ra1 = *(const uint4*)Ag1;
  uint4 rb0 = *(const uint4*)Bg0;
  uint4 rb1 = *(const uint4*)Bg1;

  for (int k0 = 0; k0 < CDIM; k0 += 32) {
    __syncthreads();
    *(uint4*)(Asm + tid * 8) = ra0;
    *(uint4*)(Asm + 2048 + tid * 8) = ra1;
    *(uint4*)(Bsm + tid * 8) = rb0;
    *(uint4*)(Bsm + 2048 + tid * 8) = rb1;
    if (k0 + 32 < CDIM) {
      ra0 = *(const uint4*)(Ag0 + k0 + 32);
      ra1 = *(const uint4*)(Ag1 + k0 + 32);
      rb0 = *(const uint4*)(Bg0 + k0 + 32);
      rb1 = *(const uint4*)(Bg1 + k0 + 32);
    }
    __syncthreads();
    f16x8_t af[4], bf[4];
#pragma unroll
    for (int mi = 0; mi < 4; mi++)
      af[mi] = *(const f16x8_t*)(Asm + (wr * 64 + mi * 16 + l15) * 32 + l4 * 8);
#pragma unroll
    for (int ni = 0; ni < 4; ni++)
      bf[ni] = *(const f16x8_t*)(Bsm + (wc * 64 + ni * 16 + l15) * 32 + l4 * 8);
#pragma unroll
    for (int mi = 0; mi < 4; mi++)
#pragma unroll
      for (int ni = 0; ni < 4; ni++)
        acc[mi][ni] = __builtin_amdgcn_mfma_f32_16x16x32_f16(
            af[mi], bf[ni], acc[mi][ni], 0, 0, 0);
  }

#pragma unroll
  for (int mi = 0; mi < 4; mi++) {
    const int mbase = m0 + wr * 64 + mi * 16 + l4 * 4;
#pragma unroll
    for (int ni = 0; ni < 4; ni++) {
      const int n = n0 + wc * 64 + ni * 16 + l15;
      if (n < NSP) {
#pragma unroll
        for (int r = 0; r < 4; r++) {
          Out[((size_t)b * CDIM + mbase + r) * NSP + n] =
              acc[mi][ni][r] + bias[mbase + r];
        }
      }
    }
  }
}

// ---------------------------------------------------------------------------
// Projection MFMA GEMM (unchanged from round 3).
// ---------------------------------------------------------------------------
__global__ __launch_bounds__(256) void gemm_proj_f16_kernel(
    const f16* __restrict__ Wp16, const f16* __restrict__ o16,
    const float* __restrict__ bias, float* __restrict__ xo,
    float* __restrict__ cls_o) {
  __shared__ __align__(16) f16 Asm[128 * 32];
  __shared__ __align__(16) f16 Bsm[128 * 32];

  const int m0 = blockIdx.y * 128;
  const int n0 = blockIdx.x * 128;
  const int tid = threadIdx.x;
  const int lane = tid & 63;
  const int w = tid >> 6;
  const int wr = w >> 1, wc = w & 1;
  const int l15 = lane & 15, l4 = lane >> 4;

  const int r0 = tid >> 2;
  const int kq = (tid & 3) * 8;
  const f16* Ag0 = Wp16 + (size_t)(m0 + r0) * CDIM + kq;
  const f16* Ag1 = Ag0 + 64 * CDIM;
  const f16* Bg0 = o16 + (size_t)(n0 + r0) * CDIM + kq;
  const f16* Bg1 = Bg0 + 64 * CDIM;

  f32x4_t acc[4][4];
#pragma unroll
  for (int i = 0; i < 4; i++)
#pragma unroll
    for (int j = 0; j < 4; j++) acc[i][j] = (f32x4_t){0.f, 0.f, 0.f, 0.f};

  uint4 ra0 = *(const uint4*)Ag0;
  uint4 ra1 = *(const uint4*)Ag1;
  uint4 rb0 = *(const uint4*)Bg0;
  uint4 rb1 = *(const uint4*)Bg1;

  for (int k0 = 0; k0 < CDIM; k0 += 32) {
    __syncthreads();
    *(uint4*)(Asm + tid * 8) = ra0;
    *(uint4*)(Asm + 2048 + tid * 8) = ra1;
    *(uint4*)(Bsm + tid * 8) = rb0;
    *(uint4*)(Bsm + 2048 + tid * 8) = rb1;
    if (k0 + 32 < CDIM) {
      ra0 = *(const uint4*)(Ag0 + k0 + 32);
      ra1 = *(const uint4*)(Ag1 + k0 + 32);
      rb0 = *(const uint4*)(Bg0 + k0 + 32);
      rb1 = *(const uint4*)(Bg1 + k0 + 32);
    }
    __syncthreads();
    f16x8_t af[4], bf[4];
#pragma unroll
    for (int mi = 0; mi < 4; mi++)
      af[mi] = *(const f16x8_t*)(Asm + (wr * 64 + mi * 16 + l15) * 32 + l4 * 8);
#pragma unroll
    for (int ni = 0; ni < 4; ni++)
      bf[ni] = *(const f16x8_t*)(Bsm + (wc * 64 + ni * 16 + l15) * 32 + l4 * 8);
#pragma unroll
    for (int mi = 0; mi < 4; mi++)
#pragma unroll
      for (int ni = 0; ni < 4; ni++)
        acc[mi][ni] = __builtin_amdgcn_mfma_f32_16x16x32_f16(
            af[mi], bf[ni], acc[mi][ni], 0, 0, 0);
  }

#pragma unroll
  for (int mi = 0; mi < 4; mi++) {
    const int mbase = m0 + wr * 64 + mi * 16 + l4 * 4;
#pragma unroll
    for (int ni = 0; ni < 4; ni++) {
      const int tok = n0 + wc * 64 + ni * 16 + l15;
      if (tok < MTOK) {
        const int bb = tok / NQTOK;
        const int nn = tok % NQTOK;
#pragma unroll
        for (int r = 0; r < 4; r++) {
          float v = acc[mi][ni][r] + bias[mbase + r];
          if (nn == 0)
            cls_o[bb * CDIM + mbase + r] = v;
          else
            xo[((size_t)bb * CDIM + mbase + r) * (size_t)NSP + nn - 1] = v;
        }
      }
    }
  }
}

// ---------------------------------------------------------------------------
// cls token linear (fp32)
// ---------------------------------------------------------------------------
__global__ __launch_bounds__(256) void cls_linear_kernel(
    const float* __restrict__ cls, const float* __restrict__ W,
    const float* __restrict__ bias, float* __restrict__ out) {
  __shared__ float xs[CDIM];
  const int b = blockIdx.x;
  for (int i = threadIdx.x; i < CDIM; i += 256) xs[i] = cls[b * CDIM + i];
  __syncthreads();
#pragma unroll
  for (int cc = 0; cc < 3; cc++) {
    int co = threadIdx.x + cc * 256;
    const float* wr = W + (size_t)co * CDIM;
    float sum = bias[co];
    for (int k = 0; k < CDIM; k += 4) {
      float4 wv = *(const float4*)&wr[k];
      float4 xv = *(const float4*)&xs[k];
      sum = fmaf(wv.x, xv.x, sum);
      sum = fmaf(wv.y, xv.y, sum);
      sum = fmaf(wv.z, xv.z, sum);
      sum = fmaf(wv.w, xv.w, sum);
    }
    out[b * CDIM + co] = sum;
  }
}

// ---------------------------------------------------------------------------
// Depthwise 3x3x3 conv (unchanged).
// ---------------------------------------------------------------------------
__global__ __launch_bounds__(256) void dwconv_kernel(
    const float* __restrict__ X, const float* __restrict__ wconv,
    float* __restrict__ Out, int Lo, int Ho, int Wo, int sh, int sw) {
  __shared__ float xin[NSP];
  __shared__ float wsm[27];
  const int c = blockIdx.x % CDIM;
  const int b = blockIdx.x / CDIM;
  const float* xb = X + ((size_t)b * CDIM + c) * (size_t)NSP;
  for (int i = threadIdx.x; i < NSP; i += 256) xin[i] = xb[i];
  if (threadIdx.x < 27) wsm[threadIdx.x] = wconv[c * 27 + threadIdx.x];
  __syncthreads();
  const int npos = Lo * Ho * Wo;
  float* ob = Out + ((size_t)b * CDIM + c) * (size_t)npos;
  for (int pos = threadIdx.x; pos < npos; pos += 256) {
    int wo = pos % Wo;
    int ho = (pos / Wo) % Ho;
    int lo = pos / (Wo * Ho);
    int li0 = lo - 1, hi0 = ho * sh - 1, wi0 = wo * sw - 1;
    float sum = 0.f;
#pragma unroll
    for (int kd = 0; kd < 3; kd++) {
      int li = li0 + kd;
      if (li < 0 || li >= LDEPTH) continue;
#pragma unroll
      for (int kh = 0; kh < 3; kh++) {
        int hi = hi0 + kh;
        if (hi < 0 || hi >= HHEIGHT) continue;
#pragma unroll
        for (int kw = 0; kw < 3; kw++) {
          int wi = wi0 + kw;
          if (wi < 0 || wi >= WWIDTH) continue;
          sum = fmaf(xin[(li * HHEIGHT + hi) * WWIDTH + wi],
                     wsm[(kd * 3 + kh) * 3 + kw], sum);
        }
      }
    }
    ob[pos] = sum;
  }
}

// ---------------------------------------------------------------------------
// In-place LayerNorm over C (unchanged).
// ---------------------------------------------------------------------------
__global__ __launch_bounds__(256) void ln_kernel(
    float* __restrict__ Y, const float* __restrict__ ln_w,
    const float* __restrict__ ln_b, int npos) {
  const int b = blockIdx.y;
  const int lane = threadIdx.x & 63;
  const int wv = threadIdx.x >> 6;
  const int pos = blockIdx.x * 64 + lane;
  const bool act = pos < npos;
  float* Yb = Y + (size_t)b * CDIM * (size_t)npos;

  float s1 = 0.f, s2 = 0.f;
  for (int c = wv; c < CDIM; c += 4) {
    float v = act ? Yb[(size_t)c * npos + pos] : 0.f;
    s1 += v;
    s2 = fmaf(v, v, s2);
  }
  __shared__ float r1[4][64], r2[4][64];
  r1[wv][lane] = s1;
  r2[wv][lane] = s2;
  __syncthreads();
  float t1 = r1[0][lane] + r1[1][lane] + r1[2][lane] + r1[3][lane];
  float t2 = r2[0][lane] + r2[1][lane] + r2[2][lane] + r2[3][lane];
  float mean = t1 * (1.f / 768.f);
  float var = t2 * (1.f / 768.f) - mean * mean;
  float rstd = rsqrtf(var + LN_EPS);
  for (int c = wv; c < CDIM; c += 4) {
    if (act) {
      size_t idx = (size_t)c * npos + pos;
      float v = Yb[idx];
      Yb[idx] = (v - mean) * rstd * ln_w[c] + ln_b[c];
    }
  }
}

// ---------------------------------------------------------------------------
// pack_q: q_pool (B,768,1568) f32 -> Qh (B,12,TQP,64) f16, t = pos+1; pad = 0.
// LDS 32x32 tile transpose. Grid (52, 24, B).
// ---------------------------------------------------------------------------
__global__ __launch_bounds__(256) void pack_q_kernel(
    const float* __restrict__ qp, f16* __restrict__ Qh) {
  __shared__ float tsm[32][33];
  const int b = blockIdx.z;
  const int c0 = blockIdx.y * 32;
  const int p0 = blockIdx.x * 32;
  const int tx = threadIdx.x & 31, ty = threadIdx.x >> 5;
#pragma unroll
  for (int i = 0; i < 4; i++) {
    int c = c0 + ty + i * 8;
    int p = p0 + tx;
    tsm[ty + i * 8][tx] = (p < NSP) ? qp[((size_t)b * CDIM + c) * NSP + p] : 0.f;
  }
  __syncthreads();
#pragma unroll
  for (int i = 0; i < 4; i++) {
    int p = p0 + ty + i * 8;
    int t = p + 1;
    if (t < TQP) {
      int c = c0 + tx;
      Qh[(((size_t)(b * NHEADS + (c >> 6))) * TQP + t) * 64 + (c & 63)] =
          (f16)tsm[tx][ty + i * 8];
    }
  }
}

// ---------------------------------------------------------------------------
// pack_k: k_pool (B,768,392) f32 -> Kh (B,12,TKP,64) f16, t = pos+1; pad = 0.
// Grid (14, 24, B).
// ---------------------------------------------------------------------------
__global__ __launch_bounds__(256) void pack_k_kernel(
    const float* __restrict__ kp, f16* __restrict__ Kh) {
  __shared__ float tsm[32][33];
  const int b = blockIdx.z;
  const int c0 = blockIdx.y * 32;
  const int p0 = blockIdx.x * 32;
  const int tx = threadIdx.x & 31, ty = threadIdx.x >> 5;
#pragma unroll
  for (int i = 0; i < 4; i++) {
    int c = c0 + ty + i * 8;
    int p = p0 + tx;
    tsm[ty + i * 8][tx] =
        (p < NKSP) ? kp[((size_t)b * CDIM + c) * NKSP + p] : 0.f;
  }
  __syncthreads();
#pragma unroll
  for (int i = 0; i < 4; i++) {
    int p = p0 + ty + i * 8;
    int t = p + 1;
    if (t < TKP) {
      int c = c0 + tx;
      Kh[(((size_t)(b * NHEADS + (c >> 6))) * TKP + t) * 64 + (c & 63)] =
          (f16)tsm[tx][ty + i * 8];
    }
  }
}

// ---------------------------------------------------------------------------
// pack_v: v_pool (B,768,392) f32 + clsv -> Vht (B,768,TKP) f16 (d-major rows).
// t=0 = cls; t in [1,392] = pool; t in [393,448) = 0. Elementwise, coalesced.
// ---------------------------------------------------------------------------
__global__ __launch_bounds__(256) void pack_v_kernel(
    const float* __restrict__ vp, const float* __restrict__ clsv,
    f16* __restrict__ Vht) {
  const size_t total = (size_t)BATCH * CDIM * TKP;
  size_t idx = (size_t)blockIdx.x * 256 + threadIdx.x;
  if (idx >= total) return;
  int t = idx % TKP;
  int c = (idx / TKP) % CDIM;
  int b = idx / ((size_t)TKP * CDIM);
  float v;
  if (t == 0)
    v = clsv[b * CDIM + c];
  else if (t <= NKSP)
    v = vp[((size_t)b * CDIM + c) * NKSP + t - 1];
  else
    v = 0.f;
  Vht[idx] = (f16)v;
}

// ---------------------------------------------------------------------------
// cls_fill: write t=0 rows of Qh and Kh from cls linear outputs.
// ---------------------------------------------------------------------------
__global__ __launch_bounds__(768) void cls_fill_kernel(
    const float* __restrict__ clsq, const float* __restrict__ clsk,
    f16* __restrict__ Qh, f16* __restrict__ Kh) {
  const int b = blockIdx.x;
  const int c = threadIdx.x;
  Qh[(((size_t)(b * NHEADS + (c >> 6))) * TQP) * 64 + (c & 63)] =
      (f16)clsq[b * CDIM + c];
  Kh[(((size_t)(b * NHEADS + (c >> 6))) * TKP) * 64 + (c & 63)] =
      (f16)clsk[b * CDIM + c];
}

// ---------------------------------------------------------------------------
// MFMA flash attention. Grid (13, 12, 8), 256 threads = 4 waves.
// Wave w: q rows [qt*128 + w*32, +32). Swapped QK^T: S^T = mfma32(K, Q) so
// D-col = q; softmax rows reduce with 2 shfl_xor; P^T is directly the
// B-fragment of mfma_f32_16x16x16_f16; PV: O^T = mfma16(V^T, P^T).
// ---------------------------------------------------------------------------
__global__ __launch_bounds__(256) void attn_mfma_kernel(
    const f16* __restrict__ Qh, const f16* __restrict__ Kh,
    const f16* __restrict__ Vht, f16* __restrict__ o16) {
  __shared__ __align__(16) f16 Ks[64 * 72];   // [key][d], pad 8
  __shared__ __align__(16) f16 Vt[64 * 72];   // [d][key], pad 8
  const int qt = blockIdx.x, h = blockIdx.y, b = blockIdx.z;
  const int tid = threadIdx.x;
  const int lane = tid & 63;
  const int w = tid >> 6;
  const int l15 = lane & 15, l4 = lane >> 4;
  const int q0 = qt * 128 + w * 32;

  const f16* Qp = Qh + ((size_t)(b * NHEADS + h) * TQP) * 64;
  const f16* Kp = Kh + ((size_t)(b * NHEADS + h) * TKP) * 64;
  const f16* Vp = Vht + ((size_t)(b * NHEADS + h) * 64) * TKP;

  // Q B-fragments (held for the whole kernel): col = q, k = d
  f16x8_t bq[2][2];
#pragma unroll
  for (int qi = 0; qi < 2; qi++)
#pragma unroll
    for (int kf = 0; kf < 2; kf++)
      bq[qi][kf] = *(const f16x8_t*)(Qp + (size_t)(q0 + qi * 16 + l15) * 64 +
                                     kf * 32 + l4 * 8);

  f32x4_t oacc[4][2];
#pragma unroll
  for (int df = 0; df < 4; df++)
#pragma unroll
    for (int qi = 0; qi < 2; qi++) oacc[df][qi] = (f32x4_t){0.f, 0.f, 0.f, 0.f};
  float mrow[2] = {-1e30f, -1e30f};
  float lrow[2] = {0.f, 0.f};

  const int sr = tid >> 2, sc = (tid & 3) * 16;

  for (int kv0 = 0; kv0 < TKP; kv0 += 64) {
    // ---- stage K tile [key][d] and V^T tile [d][key] ----
    const f16* kg = Kp + (size_t)(kv0 + sr) * 64 + sc;
    uint4 kl0 = *(const uint4*)kg;
    uint4 kl1 = *(const uint4*)(kg + 8);
    const f16* vg = Vp + (size_t)sr * TKP + kv0 + sc;
    uint4 vl0 = *(const uint4*)vg;
    uint4 vl1 = *(const uint4*)(vg + 8);
    __syncthreads();   // previous tile's reads done
    *(uint4*)(Ks + sr * 72 + sc) = kl0;
    *(uint4*)(Ks + sr * 72 + sc + 8) = kl1;
    *(uint4*)(Vt + sr * 72 + sc) = vl0;
    *(uint4*)(Vt + sr * 72 + sc + 8) = vl1;
    __syncthreads();

    // ---- S^T = K * Q^T : D[row=key][col=q] ----
    f32x4_t sacc[4][2];
#pragma unroll
    for (int ki = 0; ki < 4; ki++)
#pragma unroll
      for (int qi = 0; qi < 2; qi++) sacc[ki][qi] = (f32x4_t){0.f, 0.f, 0.f, 0.f};
#pragma unroll
    for (int kf = 0; kf < 2; kf++) {
#pragma unroll
      for (int ki = 0; ki < 4; ki++) {
        f16x8_t ak =
            *(const f16x8_t*)(Ks + (ki * 16 + l15) * 72 + kf * 32 + l4 * 8);
#pragma unroll
        for (int qi = 0; qi < 2; qi++)
          sacc[ki][qi] = __builtin_amdgcn_mfma_f32_16x16x32_f16(
              ak, bq[qi][kf], sacc[ki][qi], 0, 0, 0);
      }
    }

    // ---- scale + mask + online softmax ----
    float pmax[2] = {-1e30f, -1e30f};
#pragma unroll
    for (int ki = 0; ki < 4; ki++) {
      const int keyb = kv0 + ki * 16 + l4 * 4;
#pragma unroll
      for (int qi = 0; qi < 2; qi++) {
#pragma unroll
        for (int rr = 0; rr < 4; rr++) {
          float s = sacc[ki][qi][rr] * ATTN_SCALE;
          if (keyb + rr >= NKTOK) s = -1e30f;
          sacc[ki][qi][rr] = s;
          pmax[qi] = fmaxf(pmax[qi], s);
        }
      }
    }
#pragma unroll
    for (int qi = 0; qi < 2; qi++) {
      pmax[qi] = fmaxf(pmax[qi], __shfl_xor(pmax[qi], 16, 64));
      pmax[qi] = fmaxf(pmax[qi], __shfl_xor(pmax[qi], 32, 64));
      float mnew = fmaxf(mrow[qi], pmax[qi]);
      float alpha = __expf(mrow[qi] - mnew);
      mrow[qi] = mnew;
      lrow[qi] *= alpha;
#pragma unroll
      for (int df = 0; df < 4; df++) {
        oacc[df][qi][0] *= alpha;
        oacc[df][qi][1] *= alpha;
        oacc[df][qi][2] *= alpha;
        oacc[df][qi][3] *= alpha;
      }
    }
    f16x4_t pb[4][2];
#pragma unroll
    for (int ki = 0; ki < 4; ki++) {
#pragma unroll
      for (int qi = 0; qi < 2; qi++) {
        float p0 = __expf(sacc[ki][qi][0] - mrow[qi]);
        float p1 = __expf(sacc[ki][qi][1] - mrow[qi]);
        float p2 = __expf(sacc[ki][qi][2] - mrow[qi]);
        float p3 = __expf(sacc[ki][qi][3] - mrow[qi]);
        lrow[qi] += p0 + p1 + p2 + p3;
        f16x4_t pv = {(f16)p0, (f16)p1, (f16)p2, (f16)p3};
        pb[ki][qi] = pv;
      }
    }

    // ---- O^T += V^T * P^T : D[row=d][col=q] ----
#pragma unroll
    for (int df = 0; df < 4; df++) {
#pragma unroll
      for (int ki = 0; ki < 4; ki++) {
        f16x4_t av =
            *(const f16x4_t*)(Vt + (df * 16 + l15) * 72 + ki * 16 + l4 * 4);
#pragma unroll
        for (int qi = 0; qi < 2; qi++)
          oacc[df][qi] = __builtin_amdgcn_mfma_f32_16x16x16f16(
              av, pb[ki][qi], oacc[df][qi], 0, 0, 0);
      }
    }
  }

  // ---- finalize ----
  float inv[2];
#pragma unroll
  for (int qi = 0; qi < 2; qi++) {
    float l = lrow[qi];
    l += __shfl_xor(l, 16, 64);
    l += __shfl_xor(l, 32, 64);
    inv[qi] = 1.f / l;
  }
#pragma unroll
  for (int qi = 0; qi < 2; qi++) {
    const int q = q0 + qi * 16 + l15;
    if (q < NQTOK) {
      f16* op = o16 + ((size_t)(b * NQTOK + q)) * CDIM + h * 64 + l4 * 4;
#pragma unroll
      for (int df = 0; df < 4; df++) {
        f16x4_t ov = {(f16)(oacc[df][qi][0] * inv[qi]),
                      (f16)(oacc[df][qi][1] * inv[qi]),
                      (f16)(oacc[df][qi][2] * inv[qi]),
                      (f16)(oacc[df][qi][3] * inv[qi])};
        *(f16x4_t*)(op + df * 16) = ov;
      }
    }
  }
}

// ---------------------------------------------------------------------------
extern "C" void kernel_launch(void* const* d_in, const int* in_sizes, int n_in,
                              void* d_out, int out_size, void* d_ws, size_t ws_size,
                              hipStream_t stream) {
  const float* x      = (const float*)d_in[0];
  const float* cls    = (const float*)d_in[1];
  const float* Wq     = (const float*)d_in[2];
  const float* bq     = (const float*)d_in[3];
  const float* Wk     = (const float*)d_in[4];
  const float* bk     = (const float*)d_in[5];
  const float* Wv     = (const float*)d_in[6];
  const float* bv     = (const float*)d_in[7];
  const float* conv_q = (const float*)d_in[8];
  const float* conv_k = (const float*)d_in[9];
  const float* conv_v = (const float*)d_in[10];
  const float* lnq_w  = (const float*)d_in[11];
  const float* lnq_b  = (const float*)d_in[12];
  const float* lnk_w  = (const float*)d_in[13];
  const float* lnk_b  = (const float*)d_in[14];
  const float* lnv_w  = (const float*)d_in[15];
  const float* lnv_b  = (const float*)d_in[16];
  const float* Wproj  = (const float*)d_in[17];
  const float* bproj  = (const float*)d_in[18];

  // Workspace layout (bytes). Total = 171,122,688 B ≈ 171.1 MB.
  char* wsb = (char*)d_ws;
  f16*   Xt     = (f16*)(wsb + 0);            // 20,447,232 B
  f16*   W16    = (f16*)(wsb + 20447232);     //  4,718,592 B
  float* q_lin  = (float*)(wsb + 25165824);   // 38,535,168 B
  float* k_lin  = (float*)(wsb + 63700992);   // 38,535,168 B
  float* v_lin  = (float*)(wsb + 102236160);  // 38,535,168 B
  float* k_pool = (float*)(wsb + 140771328);  //  9,633,792 B
  float* v_pool = (float*)(wsb + 150405120);  //  9,633,792 B
  float* clsq   = (float*)(wsb + 160038912);  //     24,576 B
  float* clsk   = (float*)(wsb + 160063488);
  float* clsv   = (float*)(wsb + 160088064);
  f16*   Kh     = (f16*)(wsb + 160112640);    //  5,505,024 B
  f16*   Vht    = (f16*)(wsb + 165617664);    //  5,505,024 B -> end 171,122,688
  float* q_pool = k_lin;   // alias: k_lin dead after dwconv_k
  f16*   Qh     = Xt;      // alias: Xt dead after QKV GEMM (same size)
  f16*   o16    = (f16*)v_lin;  // alias: v_lin dead after dwconv_v

  f16* W16q = W16;
  f16* W16k = W16 + (size_t)WELEM;
  f16* W16v = W16 + (size_t)2 * WELEM;
  f16* W16p = W16 + (size_t)3 * WELEM;

  // 1. convert weights to fp16
  convert_f16_kernel<<<576, 256, 0, stream>>>(Wq, W16q, WELEM);
  convert_f16_kernel<<<576, 256, 0, stream>>>(Wk, W16k, WELEM);
  convert_f16_kernel<<<576, 256, 0, stream>>>(Wv, W16v, WELEM);
  convert_f16_kernel<<<576, 256, 0, stream>>>(Wproj, W16p, WELEM);

  // 2. transpose+convert X -> Xt
  transpose_x_kernel<<<dim3(52, 24, BATCH), 256, 0, stream>>>(x, Xt);

  // 3. fused QKV MFMA GEMM
  gemm_qkv_f16_kernel<<<dim3(13, 18, BATCH), 256, 0, stream>>>(
      W16, Xt, bq, bk, bv, q_lin);

  // 4. cls token linears
  cls_linear_kernel<<<BATCH, 256, 0, stream>>>(cls, Wq, bq, clsq);
  cls_linear_kernel<<<BATCH, 256, 0, stream>>>(cls, Wk, bk, clsk);
  cls_linear_kernel<<<BATCH, 256, 0, stream>>>(cls, Wv, bv, clsv);

  // 5. depthwise convs (k first, then q overwrites k_lin via alias)
  dwconv_kernel<<<BATCH * CDIM, 256, 0, stream>>>(k_lin, conv_k, k_pool,
                                                  8, 7, 7, 2, 2);
  dwconv_kernel<<<BATCH * CDIM, 256, 0, stream>>>(v_lin, conv_v, v_pool,
                                                  8, 7, 7, 2, 2);
  dwconv_kernel<<<BATCH * CDIM, 256, 0, stream>>>(q_lin, conv_q, q_pool,
                                                  8, 14, 14, 1, 1);

  // 6. layernorms (in place)
  ln_kernel<<<dim3(25, BATCH), 256, 0, stream>>>(q_pool, lnq_w, lnq_b, NSP);
  ln_kernel<<<dim3(7, BATCH), 256, 0, stream>>>(k_pool, lnk_w, lnk_b, NKSP);
  ln_kernel<<<dim3(7, BATCH), 256, 0, stream>>>(v_pool, lnv_w, lnv_b, NKSP);

  // 7. pack to attention layouts (f16)
  pack_q_kernel<<<dim3(52, 24, BATCH), 256, 0, stream>>>(q_pool, Qh);
  pack_k_kernel<<<dim3(14, 24, BATCH), 256, 0, stream>>>(k_pool, Kh);
  {
    const size_t total = (size_t)BATCH * CDIM * TKP;
    pack_v_kernel<<<(int)((total + 255) / 256), 256, 0, stream>>>(v_pool, clsv,
                                                                  Vht);
  }
  cls_fill_kernel<<<BATCH, 768, 0, stream>>>(clsq, clsk, Qh, Kh);

  // 8. MFMA attention -> o16 (token-major f16, aliases v_lin)
  attn_mfma_kernel<<<dim3(13, NHEADS, BATCH), 256, 0, stream>>>(Qh, Kh, Vht,
                                                                o16);

  // 9. projection MFMA GEMM -> d_out
  float* xo = (float*)d_out;
  float* cls_o = (float*)d_out + (size_t)BATCH * CDIM * NSP;
  gemm_proj_f16_kernel<<<dim3(99, 6), 256, 0, stream>>>(W16p, o16, bproj, xo,
                                                        cls_o);
}

// Round 5
// 644.017 us; speedup vs baseline: 6.9749x; 1.2707x over previous
//
#include <hip/hip_runtime.h>

#define CDIM 768
#define BATCH 8
#define LDEPTH 8
#define HHEIGHT 14
#define WWIDTH 14
#define NSP 1568      // 8*14*14 spatial tokens (input / q)
#define NQTOK 1569    // +cls
#define NKSP 392      // 8*7*7 spatial tokens (k/v after pool)
#define NKTOK 393
#define NHEADS 12
#define HEADDIM 64
#define ATTN_SCALE 0.125f
#define LN_EPS 1e-6f
#define MTOK (BATCH * NQTOK)   // 12552 tokens for proj GEMM
#define NPAD_X 1664            // Xt padded rows per batch (13 tiles * 128)
#define NPAD_TOK 12672         // o16 padded tokens (99 tiles * 128)
#define WELEM (CDIM * CDIM)    // 589824
#define TQP 1664               // padded q tokens per (b,h)  (13*128)
#define TKP 448                // padded kv tokens per (b,h) (7*64)

typedef _Float16 f16;
typedef _Float16 f16x8_t __attribute__((ext_vector_type(8)));
typedef _Float16 f16x4_t __attribute__((ext_vector_type(4)));
typedef float f32x4_t __attribute__((ext_vector_type(4)));

// ---------------------------------------------------------------------------
// fp32 -> fp16 convert (for weight matrices)
// ---------------------------------------------------------------------------
__global__ __launch_bounds__(256) void convert_f16_kernel(
    const float* __restrict__ src, f16* __restrict__ dst, int n) {
  int i = (blockIdx.x * 256 + threadIdx.x) * 4;
  if (i < n) {
    float4 v = *(const float4*)&src[i];
    f16x4_t h = {(f16)v.x, (f16)v.y, (f16)v.z, (f16)v.w};
    *(f16x4_t*)&dst[i] = h;
  }
}

// ---------------------------------------------------------------------------
// Transpose+convert X: (B,768,1568) f32 -> Xt (B,1664,768) f16, pad rows = 0.
// ---------------------------------------------------------------------------
__global__ __launch_bounds__(256) void transpose_x_kernel(
    const float* __restrict__ X, f16* __restrict__ Xt) {
  __shared__ float t[32][33];
  const int b = blockIdx.z;
  const int k0 = blockIdx.y * 32;
  const int n0 = blockIdx.x * 32;
  const int tx = threadIdx.x & 31, ty = threadIdx.x >> 5;
#pragma unroll
  for (int i = 0; i < 4; i++) {
    int k = k0 + ty + i * 8;
    int n = n0 + tx;
    t[ty + i * 8][tx] = (n < NSP) ? X[((size_t)b * CDIM + k) * NSP + n] : 0.f;
  }
  __syncthreads();
#pragma unroll
  for (int i = 0; i < 4; i++) {
    int n = n0 + ty + i * 8;
    Xt[((size_t)b * NPAD_X + n) * CDIM + k0 + tx] = (f16)t[tx][ty + i * 8];
  }
}

// ---------------------------------------------------------------------------
// Fused QKV MFMA GEMM.
// ---------------------------------------------------------------------------
__global__ __launch_bounds__(256) void gemm_qkv_f16_kernel(
    const f16* __restrict__ W16, const f16* __restrict__ Xt,
    const float* __restrict__ bq, const float* __restrict__ bk,
    const float* __restrict__ bv, float* __restrict__ OutBase) {
  __shared__ __align__(16) f16 Asm[128 * 32];
  __shared__ __align__(16) f16 Bsm[128 * 32];

  const int b = blockIdx.z;
  const int mat = blockIdx.y / 6;
  const int m0 = (blockIdx.y % 6) * 128;
  const int n0 = blockIdx.x * 128;
  const int tid = threadIdx.x;
  const int lane = tid & 63;
  const int w = tid >> 6;
  const int wr = w >> 1, wc = w & 1;
  const int l15 = lane & 15, l4 = lane >> 4;

  const f16* A16 = W16 + (size_t)mat * WELEM;
  const float* bias = (mat == 0) ? bq : (mat == 1) ? bk : bv;
  float* Out = OutBase + (size_t)mat * ((size_t)BATCH * CDIM * NSP);

  const int r0 = tid >> 2;
  const int kq = (tid & 3) * 8;
  const f16* Ag0 = A16 + (size_t)(m0 + r0) * CDIM + kq;
  const f16* Ag1 = Ag0 + 64 * CDIM;
  const f16* Bg0 = Xt + ((size_t)b * NPAD_X + n0 + r0) * CDIM + kq;
  const f16* Bg1 = Bg0 + 64 * CDIM;

  f32x4_t acc[4][4];
#pragma unroll
  for (int i = 0; i < 4; i++)
#pragma unroll
    for (int j = 0; j < 4; j++) acc[i][j] = (f32x4_t){0.f, 0.f, 0.f, 0.f};

  uint4 ra0 = *(const uint4*)Ag0;
  uint4 ra1 = *(const uint4*)Ag1;
  uint4 rb0 = *(const uint4*)Bg0;
  uint4 rb1 = *(const uint4*)Bg1;

  for (int k0 = 0; k0 < CDIM; k0 += 32) {
    __syncthreads();
    *(uint4*)(Asm + tid * 8) = ra0;
    *(uint4*)(Asm + 2048 + tid * 8) = ra1;
    *(uint4*)(Bsm + tid * 8) = rb0;
    *(uint4*)(Bsm + 2048 + tid * 8) = rb1;
    if (k0 + 32 < CDIM) {
      ra0 = *(const uint4*)(Ag0 + k0 + 32);
      ra1 = *(const uint4*)(Ag1 + k0 + 32);
      rb0 = *(const uint4*)(Bg0 + k0 + 32);
      rb1 = *(const uint4*)(Bg1 + k0 + 32);
    }
    __syncthreads();
    f16x8_t af[4], bf[4];
#pragma unroll
    for (int mi = 0; mi < 4; mi++)
      af[mi] = *(const f16x8_t*)(Asm + (wr * 64 + mi * 16 + l15) * 32 + l4 * 8);
#pragma unroll
    for (int ni = 0; ni < 4; ni++)
      bf[ni] = *(const f16x8_t*)(Bsm + (wc * 64 + ni * 16 + l15) * 32 + l4 * 8);
#pragma unroll
    for (int mi = 0; mi < 4; mi++)
#pragma unroll
      for (int ni = 0; ni < 4; ni++)
        acc[mi][ni] = __builtin_amdgcn_mfma_f32_16x16x32_f16(
            af[mi], bf[ni], acc[mi][ni], 0, 0, 0);
  }

#pragma unroll
  for (int mi = 0; mi < 4; mi++) {
    const int mbase = m0 + wr * 64 + mi * 16 + l4 * 4;
#pragma unroll
    for (int ni = 0; ni < 4; ni++) {
      const int n = n0 + wc * 64 + ni * 16 + l15;
      if (n < NSP) {
#pragma unroll
        for (int r = 0; r < 4; r++) {
          Out[((size_t)b * CDIM + mbase + r) * NSP + n] =
              acc[mi][ni][r] + bias[mbase + r];
        }
      }
    }
  }
}

// ---------------------------------------------------------------------------
// Projection MFMA GEMM.
// ---------------------------------------------------------------------------
__global__ __launch_bounds__(256) void gemm_proj_f16_kernel(
    const f16* __restrict__ Wp16, const f16* __restrict__ o16,
    const float* __restrict__ bias, float* __restrict__ xo,
    float* __restrict__ cls_o) {
  __shared__ __align__(16) f16 Asm[128 * 32];
  __shared__ __align__(16) f16 Bsm[128 * 32];

  const int m0 = blockIdx.y * 128;
  const int n0 = blockIdx.x * 128;
  const int tid = threadIdx.x;
  const int lane = tid & 63;
  const int w = tid >> 6;
  const int wr = w >> 1, wc = w & 1;
  const int l15 = lane & 15, l4 = lane >> 4;

  const int r0 = tid >> 2;
  const int kq = (tid & 3) * 8;
  const f16* Ag0 = Wp16 + (size_t)(m0 + r0) * CDIM + kq;
  const f16* Ag1 = Ag0 + 64 * CDIM;
  const f16* Bg0 = o16 + (size_t)(n0 + r0) * CDIM + kq;
  const f16* Bg1 = Bg0 + 64 * CDIM;

  f32x4_t acc[4][4];
#pragma unroll
  for (int i = 0; i < 4; i++)
#pragma unroll
    for (int j = 0; j < 4; j++) acc[i][j] = (f32x4_t){0.f, 0.f, 0.f, 0.f};

  uint4 ra0 = *(const uint4*)Ag0;
  uint4 ra1 = *(const uint4*)Ag1;
  uint4 rb0 = *(const uint4*)Bg0;
  uint4 rb1 = *(const uint4*)Bg1;

  for (int k0 = 0; k0 < CDIM; k0 += 32) {
    __syncthreads();
    *(uint4*)(Asm + tid * 8) = ra0;
    *(uint4*)(Asm + 2048 + tid * 8) = ra1;
    *(uint4*)(Bsm + tid * 8) = rb0;
    *(uint4*)(Bsm + 2048 + tid * 8) = rb1;
    if (k0 + 32 < CDIM) {
      ra0 = *(const uint4*)(Ag0 + k0 + 32);
      ra1 = *(const uint4*)(Ag1 + k0 + 32);
      rb0 = *(const uint4*)(Bg0 + k0 + 32);
      rb1 = *(const uint4*)(Bg1 + k0 + 32);
    }
    __syncthreads();
    f16x8_t af[4], bf[4];
#pragma unroll
    for (int mi = 0; mi < 4; mi++)
      af[mi] = *(const f16x8_t*)(Asm + (wr * 64 + mi * 16 + l15) * 32 + l4 * 8);
#pragma unroll
    for (int ni = 0; ni < 4; ni++)
      bf[ni] = *(const f16x8_t*)(Bsm + (wc * 64 + ni * 16 + l15) * 32 + l4 * 8);
#pragma unroll
    for (int mi = 0; mi < 4; mi++)
#pragma unroll
      for (int ni = 0; ni < 4; ni++)
        acc[mi][ni] = __builtin_amdgcn_mfma_f32_16x16x32_f16(
            af[mi], bf[ni], acc[mi][ni], 0, 0, 0);
  }

#pragma unroll
  for (int mi = 0; mi < 4; mi++) {
    const int mbase = m0 + wr * 64 + mi * 16 + l4 * 4;
#pragma unroll
    for (int ni = 0; ni < 4; ni++) {
      const int tok = n0 + wc * 64 + ni * 16 + l15;
      if (tok < MTOK) {
        const int bb = tok / NQTOK;
        const int nn = tok % NQTOK;
#pragma unroll
        for (int r = 0; r < 4; r++) {
          float v = acc[mi][ni][r] + bias[mbase + r];
          if (nn == 0)
            cls_o[bb * CDIM + mbase + r] = v;
          else
            xo[((size_t)bb * CDIM + mbase + r) * (size_t)NSP + nn - 1] = v;
        }
      }
    }
  }
}

// ---------------------------------------------------------------------------
// cls token linear (fp32)
// ---------------------------------------------------------------------------
__global__ __launch_bounds__(256) void cls_linear_kernel(
    const float* __restrict__ cls, const float* __restrict__ W,
    const float* __restrict__ bias, float* __restrict__ out) {
  __shared__ float xs[CDIM];
  const int b = blockIdx.x;
  for (int i = threadIdx.x; i < CDIM; i += 256) xs[i] = cls[b * CDIM + i];
  __syncthreads();
#pragma unroll
  for (int cc = 0; cc < 3; cc++) {
    int co = threadIdx.x + cc * 256;
    const float* wr = W + (size_t)co * CDIM;
    float sum = bias[co];
    for (int k = 0; k < CDIM; k += 4) {
      float4 wv = *(const float4*)&wr[k];
      float4 xv = *(const float4*)&xs[k];
      sum = fmaf(wv.x, xv.x, sum);
      sum = fmaf(wv.y, xv.y, sum);
      sum = fmaf(wv.z, xv.z, sum);
      sum = fmaf(wv.w, xv.w, sum);
    }
    out[b * CDIM + co] = sum;
  }
}

// ---------------------------------------------------------------------------
// Depthwise 3x3x3 conv.
// ---------------------------------------------------------------------------
__global__ __launch_bounds__(256) void dwconv_kernel(
    const float* __restrict__ X, const float* __restrict__ wconv,
    float* __restrict__ Out, int Lo, int Ho, int Wo, int sh, int sw) {
  __shared__ float xin[NSP];
  __shared__ float wsm[27];
  const int c = blockIdx.x % CDIM;
  const int b = blockIdx.x / CDIM;
  const float* xb = X + ((size_t)b * CDIM + c) * (size_t)NSP;
  for (int i = threadIdx.x; i < NSP; i += 256) xin[i] = xb[i];
  if (threadIdx.x < 27) wsm[threadIdx.x] = wconv[c * 27 + threadIdx.x];
  __syncthreads();
  const int npos = Lo * Ho * Wo;
  float* ob = Out + ((size_t)b * CDIM + c) * (size_t)npos;
  for (int pos = threadIdx.x; pos < npos; pos += 256) {
    int wo = pos % Wo;
    int ho = (pos / Wo) % Ho;
    int lo = pos / (Wo * Ho);
    int li0 = lo - 1, hi0 = ho * sh - 1, wi0 = wo * sw - 1;
    float sum = 0.f;
#pragma unroll
    for (int kd = 0; kd < 3; kd++) {
      int li = li0 + kd;
      if (li < 0 || li >= LDEPTH) continue;
#pragma unroll
      for (int kh = 0; kh < 3; kh++) {
        int hi = hi0 + kh;
        if (hi < 0 || hi >= HHEIGHT) continue;
#pragma unroll
        for (int kw = 0; kw < 3; kw++) {
          int wi = wi0 + kw;
          if (wi < 0 || wi >= WWIDTH) continue;
          sum = fmaf(xin[(li * HHEIGHT + hi) * WWIDTH + wi],
                     wsm[(kd * 3 + kh) * 3 + kw], sum);
        }
      }
    }
    ob[pos] = sum;
  }
}

// ---------------------------------------------------------------------------
// Fused LayerNorm + head-pack for q/k: read pool (B,768,np) f32, LN over C
// per position, write OutH (B,12,tp,64) f16 at t = pos+1.
// Grid (ceil(np/32), B), block 256. Phase 1: stats (8 channel-groups x 32
// pos). Phase 2: per-head re-read (L2-hot), normalize, LDS transpose tile
// [32][72] (stride 9x16B units, gcd(9,8)=1 -> conflict-floor), 128B-row
// coalesced writes.
// ---------------------------------------------------------------------------
__global__ __launch_bounds__(256) void ln_pack_qk_kernel(
    const float* __restrict__ xp, const float* __restrict__ ln_w,
    const float* __restrict__ ln_b, f16* __restrict__ OutH, int np, int tp) {
  const int b = blockIdx.y;
  const int p0 = blockIdx.x * 32;
  const int tid = threadIdx.x;
  const int pl = tid & 31;
  const int grp = tid >> 5;
  const int pos = p0 + pl;
  const bool act = pos < np;
  const float* Xb = xp + (size_t)b * CDIM * (size_t)np;

  __shared__ float r1[8][33], r2[8][33];
  __shared__ float smean[32], srstd[32];
  __shared__ __align__(16) f16 tile[32][72];

  float s1 = 0.f, s2 = 0.f;
  if (act) {
    for (int c = grp; c < CDIM; c += 8) {
      float v = Xb[(size_t)c * np + pos];
      s1 += v;
      s2 = fmaf(v, v, s2);
    }
  }
  r1[grp][pl] = s1;
  r2[grp][pl] = s2;
  __syncthreads();
  if (tid < 32) {
    float t1 = 0.f, t2 = 0.f;
#pragma unroll
    for (int g = 0; g < 8; g++) { t1 += r1[g][tid]; t2 += r2[g][tid]; }
    float mean = t1 * (1.f / 768.f);
    float var = t2 * (1.f / 768.f) - mean * mean;
    smean[tid] = mean;
    srstd[tid] = rsqrtf(var + LN_EPS);
  }
  __syncthreads();
  const float mean = smean[pl], rstd = srstd[pl];
  const int tl = tid >> 3, d8 = (tid & 7) * 8;

  for (int h = 0; h < NHEADS; h++) {
    f16x8_t hv;
#pragma unroll
    for (int i = 0; i < 8; i++) {
      int c = h * 64 + grp * 8 + i;
      float v = act ? Xb[(size_t)c * np + pos] : 0.f;
      hv[i] = (f16)((v - mean) * rstd * ln_w[c] + ln_b[c]);
    }
    *(f16x8_t*)&tile[pl][grp * 8] = hv;
    __syncthreads();
    if (p0 + tl < np) {
      uint4 vv = *(const uint4*)&tile[tl][d8];
      *(uint4*)(OutH +
                (((size_t)(b * NHEADS + h)) * (size_t)tp + (p0 + tl + 1)) * 64 +
                d8) = vv;
    }
    __syncthreads();
  }
}

// ---------------------------------------------------------------------------
// Fused LayerNorm + transpose-pack for v: read v_pool (B,768,392) f32 + clsv,
// write Vht (B,768,448) f16 ([c][t], t=0 = cls raw (no LN), t in [1,392] =
// LN'd pos t-1, t >= 393 = 0). t-aligned 32-token blocks -> 16B-aligned
// uint4 global writes. Grid (14, B).
// ---------------------------------------------------------------------------
__global__ __launch_bounds__(256) void ln_pack_v_kernel(
    const float* __restrict__ vp, const float* __restrict__ clsv,
    const float* __restrict__ ln_w, const float* __restrict__ ln_b,
    f16* __restrict__ Vht) {
  const int b = blockIdx.y;
  const int t0 = blockIdx.x * 32;
  const int tid = threadIdx.x;
  const int pl = tid & 31;
  const int grp = tid >> 5;
  const int t = t0 + pl;
  const int pos = t - 1;
  const bool isv = (t >= 1) && (t < NKTOK);
  const float* Vb = vp + (size_t)b * CDIM * (size_t)NKSP;

  __shared__ float r1[8][33], r2[8][33];
  __shared__ float smean[32], srstd[32];
  __shared__ __align__(16) f16 vtile[128][40];  // 5x16B rows, gcd(5,8)=1

  float s1 = 0.f, s2 = 0.f;
  if (isv) {
    for (int c = grp; c < CDIM; c += 8) {
      float v = Vb[(size_t)c * NKSP + pos];
      s1 += v;
      s2 = fmaf(v, v, s2);
    }
  }
  r1[grp][pl] = s1;
  r2[grp][pl] = s2;
  __syncthreads();
  if (tid < 32) {
    float t1 = 0.f, t2 = 0.f;
#pragma unroll
    for (int g = 0; g < 8; g++) { t1 += r1[g][tid]; t2 += r2[g][tid]; }
    float mean = t1 * (1.f / 768.f);
    float var = t2 * (1.f / 768.f) - mean * mean;
    smean[tid] = mean;
    srstd[tid] = rsqrtf(var + LN_EPS);
  }
  __syncthreads();
  const float mean = smean[pl], rstd = srstd[pl];

  for (int cc = 0; cc < 6; cc++) {
#pragma unroll
    for (int i = 0; i < 16; i++) {
      int cl = grp * 16 + i;
      int c = cc * 128 + cl;
      float outv;
      if (isv)
        outv = (Vb[(size_t)c * NKSP + pos] - mean) * rstd * ln_w[c] + ln_b[c];
      else if (t == 0)
        outv = clsv[b * CDIM + c];
      else
        outv = 0.f;
      vtile[cl][pl] = (f16)outv;
    }
    __syncthreads();
#pragma unroll
    for (int it = 0; it < 2; it++) {
      int idx = it * 256 + tid;
      int cl = idx >> 2, t8 = (idx & 3) * 8;
      uint4 vv = *(const uint4*)&vtile[cl][t8];
      *(uint4*)(Vht + ((size_t)b * CDIM + cc * 128 + cl) * (size_t)TKP + t0 +
                t8) = vv;
    }
    __syncthreads();
  }
}

// ---------------------------------------------------------------------------
// cls_fill: write t=0 rows of Qh and Kh from cls linear outputs.
// ---------------------------------------------------------------------------
__global__ __launch_bounds__(768) void cls_fill_kernel(
    const float* __restrict__ clsq, const float* __restrict__ clsk,
    f16* __restrict__ Qh, f16* __restrict__ Kh) {
  const int b = blockIdx.x;
  const int c = threadIdx.x;
  Qh[(((size_t)(b * NHEADS + (c >> 6))) * TQP) * 64 + (c & 63)] =
      (f16)clsq[b * CDIM + c];
  Kh[(((size_t)(b * NHEADS + (c >> 6))) * TKP) * 64 + (c & 63)] =
      (f16)clsk[b * CDIM + c];
}

// ---------------------------------------------------------------------------
// MFMA flash attention. Grid (13, 12, 8), 256 threads = 4 waves.
// ---------------------------------------------------------------------------
__global__ __launch_bounds__(256) void attn_mfma_kernel(
    const f16* __restrict__ Qh, const f16* __restrict__ Kh,
    const f16* __restrict__ Vht, f16* __restrict__ o16) {
  __shared__ __align__(16) f16 Ks[64 * 72];   // [key][d], pad 8
  __shared__ __align__(16) f16 Vt[64 * 72];   // [d][key], pad 8
  const int qt = blockIdx.x, h = blockIdx.y, b = blockIdx.z;
  const int tid = threadIdx.x;
  const int lane = tid & 63;
  const int w = tid >> 6;
  const int l15 = lane & 15, l4 = lane >> 4;
  const int q0 = qt * 128 + w * 32;

  const f16* Qp = Qh + ((size_t)(b * NHEADS + h) * TQP) * 64;
  const f16* Kp = Kh + ((size_t)(b * NHEADS + h) * TKP) * 64;
  const f16* Vp = Vht + ((size_t)(b * NHEADS + h) * 64) * TKP;

  f16x8_t bq[2][2];
#pragma unroll
  for (int qi = 0; qi < 2; qi++)
#pragma unroll
    for (int kf = 0; kf < 2; kf++)
      bq[qi][kf] = *(const f16x8_t*)(Qp + (size_t)(q0 + qi * 16 + l15) * 64 +
                                     kf * 32 + l4 * 8);

  f32x4_t oacc[4][2];
#pragma unroll
  for (int df = 0; df < 4; df++)
#pragma unroll
    for (int qi = 0; qi < 2; qi++) oacc[df][qi] = (f32x4_t){0.f, 0.f, 0.f, 0.f};
  float mrow[2] = {-1e30f, -1e30f};
  float lrow[2] = {0.f, 0.f};

  const int sr = tid >> 2, sc = (tid & 3) * 16;

  for (int kv0 = 0; kv0 < TKP; kv0 += 64) {
    const f16* kg = Kp + (size_t)(kv0 + sr) * 64 + sc;
    uint4 kl0 = *(const uint4*)kg;
    uint4 kl1 = *(const uint4*)(kg + 8);
    const f16* vg = Vp + (size_t)sr * TKP + kv0 + sc;
    uint4 vl0 = *(const uint4*)vg;
    uint4 vl1 = *(const uint4*)(vg + 8);
    __syncthreads();
    *(uint4*)(Ks + sr * 72 + sc) = kl0;
    *(uint4*)(Ks + sr * 72 + sc + 8) = kl1;
    *(uint4*)(Vt + sr * 72 + sc) = vl0;
    *(uint4*)(Vt + sr * 72 + sc + 8) = vl1;
    __syncthreads();

    f32x4_t sacc[4][2];
#pragma unroll
    for (int ki = 0; ki < 4; ki++)
#pragma unroll
      for (int qi = 0; qi < 2; qi++) sacc[ki][qi] = (f32x4_t){0.f, 0.f, 0.f, 0.f};
#pragma unroll
    for (int kf = 0; kf < 2; kf++) {
#pragma unroll
      for (int ki = 0; ki < 4; ki++) {
        f16x8_t ak =
            *(const f16x8_t*)(Ks + (ki * 16 + l15) * 72 + kf * 32 + l4 * 8);
#pragma unroll
        for (int qi = 0; qi < 2; qi++)
          sacc[ki][qi] = __builtin_amdgcn_mfma_f32_16x16x32_f16(
              ak, bq[qi][kf], sacc[ki][qi], 0, 0, 0);
      }
    }

    float pmax[2] = {-1e30f, -1e30f};
#pragma unroll
    for (int ki = 0; ki < 4; ki++) {
      const int keyb = kv0 + ki * 16 + l4 * 4;
#pragma unroll
      for (int qi = 0; qi < 2; qi++) {
#pragma unroll
        for (int rr = 0; rr < 4; rr++) {
          float s = sacc[ki][qi][rr] * ATTN_SCALE;
          if (keyb + rr >= NKTOK) s = -1e30f;
          sacc[ki][qi][rr] = s;
          pmax[qi] = fmaxf(pmax[qi], s);
        }
      }
    }
#pragma unroll
    for (int qi = 0; qi < 2; qi++) {
      pmax[qi] = fmaxf(pmax[qi], __shfl_xor(pmax[qi], 16, 64));
      pmax[qi] = fmaxf(pmax[qi], __shfl_xor(pmax[qi], 32, 64));
      float mnew = fmaxf(mrow[qi], pmax[qi]);
      float alpha = __expf(mrow[qi] - mnew);
      mrow[qi] = mnew;
      lrow[qi] *= alpha;
#pragma unroll
      for (int df = 0; df < 4; df++) {
        oacc[df][qi][0] *= alpha;
        oacc[df][qi][1] *= alpha;
        oacc[df][qi][2] *= alpha;
        oacc[df][qi][3] *= alpha;
      }
    }
    f16x4_t pb[4][2];
#pragma unroll
    for (int ki = 0; ki < 4; ki++) {
#pragma unroll
      for (int qi = 0; qi < 2; qi++) {
        float p0 = __expf(sacc[ki][qi][0] - mrow[qi]);
        float p1 = __expf(sacc[ki][qi][1] - mrow[qi]);
        float p2 = __expf(sacc[ki][qi][2] - mrow[qi]);
        float p3 = __expf(sacc[ki][qi][3] - mrow[qi]);
        lrow[qi] += p0 + p1 + p2 + p3;
        f16x4_t pv = {(f16)p0, (f16)p1, (f16)p2, (f16)p3};
        pb[ki][qi] = pv;
      }
    }

#pragma unroll
    for (int df = 0; df < 4; df++) {
#pragma unroll
      for (int ki = 0; ki < 4; ki++) {
        f16x4_t av =
            *(const f16x4_t*)(Vt + (df * 16 + l15) * 72 + ki * 16 + l4 * 4);
#pragma unroll
        for (int qi = 0; qi < 2; qi++)
          oacc[df][qi] = __builtin_amdgcn_mfma_f32_16x16x16f16(
              av, pb[ki][qi], oacc[df][qi], 0, 0, 0);
      }
    }
  }

  float inv[2];
#pragma unroll
  for (int qi = 0; qi < 2; qi++) {
    float l = lrow[qi];
    l += __shfl_xor(l, 16, 64);
    l += __shfl_xor(l, 32, 64);
    inv[qi] = 1.f / l;
  }
#pragma unroll
  for (int qi = 0; qi < 2; qi++) {
    const int q = q0 + qi * 16 + l15;
    if (q < NQTOK) {
      f16* op = o16 + ((size_t)(b * NQTOK + q)) * CDIM + h * 64 + l4 * 4;
#pragma unroll
      for (int df = 0; df < 4; df++) {
        f16x4_t ov = {(f16)(oacc[df][qi][0] * inv[qi]),
                      (f16)(oacc[df][qi][1] * inv[qi]),
                      (f16)(oacc[df][qi][2] * inv[qi]),
                      (f16)(oacc[df][qi][3] * inv[qi])};
        *(f16x4_t*)(op + df * 16) = ov;
      }
    }
  }
}

// ---------------------------------------------------------------------------
extern "C" void kernel_launch(void* const* d_in, const int* in_sizes, int n_in,
                              void* d_out, int out_size, void* d_ws, size_t ws_size,
                              hipStream_t stream) {
  const float* x      = (const float*)d_in[0];
  const float* cls    = (const float*)d_in[1];
  const float* Wq     = (const float*)d_in[2];
  const float* bq     = (const float*)d_in[3];
  const float* Wk     = (const float*)d_in[4];
  const float* bk     = (const float*)d_in[5];
  const float* Wv     = (const float*)d_in[6];
  const float* bv     = (const float*)d_in[7];
  const float* conv_q = (const float*)d_in[8];
  const float* conv_k = (const float*)d_in[9];
  const float* conv_v = (const float*)d_in[10];
  const float* lnq_w  = (const float*)d_in[11];
  const float* lnq_b  = (const float*)d_in[12];
  const float* lnk_w  = (const float*)d_in[13];
  const float* lnk_b  = (const float*)d_in[14];
  const float* lnv_w  = (const float*)d_in[15];
  const float* lnv_b  = (const float*)d_in[16];
  const float* Wproj  = (const float*)d_in[17];
  const float* bproj  = (const float*)d_in[18];

  // Workspace layout (bytes). Total = 171,122,688 B.
  char* wsb = (char*)d_ws;
  f16*   Xt     = (f16*)(wsb + 0);            // 20,447,232 B
  f16*   W16    = (f16*)(wsb + 20447232);     //  4,718,592 B
  float* q_lin  = (float*)(wsb + 25165824);   // 38,535,168 B
  float* k_lin  = (float*)(wsb + 63700992);   // 38,535,168 B
  float* v_lin  = (float*)(wsb + 102236160);  // 38,535,168 B
  float* k_pool = (float*)(wsb + 140771328);  //  9,633,792 B
  float* v_pool = (float*)(wsb + 150405120);  //  9,633,792 B
  float* clsq   = (float*)(wsb + 160038912);  //     24,576 B
  float* clsk   = (float*)(wsb + 160063488);
  float* clsv   = (float*)(wsb + 160088064);
  f16*   Kh     = (f16*)(wsb + 160112640);    //  5,505,024 B
  f16*   Vht    = (f16*)(wsb + 165617664);    //  5,505,024 B
  float* q_pool = k_lin;   // alias: k_lin dead after dwconv_k
  f16*   Qh     = Xt;      // alias: Xt dead after QKV GEMM
  f16*   o16    = (f16*)v_lin;  // alias: v_lin dead after dwconv_v

  f16* W16q = W16;
  f16* W16k = W16 + (size_t)WELEM;
  f16* W16v = W16 + (size_t)2 * WELEM;
  f16* W16p = W16 + (size_t)3 * WELEM;

  // 1. convert weights to fp16
  convert_f16_kernel<<<576, 256, 0, stream>>>(Wq, W16q, WELEM);
  convert_f16_kernel<<<576, 256, 0, stream>>>(Wk, W16k, WELEM);
  convert_f16_kernel<<<576, 256, 0, stream>>>(Wv, W16v, WELEM);
  convert_f16_kernel<<<576, 256, 0, stream>>>(Wproj, W16p, WELEM);

  // 2. transpose+convert X -> Xt
  transpose_x_kernel<<<dim3(52, 24, BATCH), 256, 0, stream>>>(x, Xt);

  // 3. fused QKV MFMA GEMM
  gemm_qkv_f16_kernel<<<dim3(13, 18, BATCH), 256, 0, stream>>>(
      W16, Xt, bq, bk, bv, q_lin);

  // 4. cls token linears
  cls_linear_kernel<<<BATCH, 256, 0, stream>>>(cls, Wq, bq, clsq);
  cls_linear_kernel<<<BATCH, 256, 0, stream>>>(cls, Wk, bk, clsk);
  cls_linear_kernel<<<BATCH, 256, 0, stream>>>(cls, Wv, bv, clsv);

  // 5. depthwise convs (k first, then q overwrites k_lin via alias)
  dwconv_kernel<<<BATCH * CDIM, 256, 0, stream>>>(k_lin, conv_k, k_pool,
                                                  8, 7, 7, 2, 2);
  dwconv_kernel<<<BATCH * CDIM, 256, 0, stream>>>(v_lin, conv_v, v_pool,
                                                  8, 7, 7, 2, 2);
  dwconv_kernel<<<BATCH * CDIM, 256, 0, stream>>>(q_lin, conv_q, q_pool,
                                                  8, 14, 14, 1, 1);

  // 6. fused LN + pack (q/k into head layout at t=pos+1; v transposed incl.
  //    cls row and zero pad)
  ln_pack_qk_kernel<<<dim3(49, BATCH), 256, 0, stream>>>(q_pool, lnq_w, lnq_b,
                                                         Qh, NSP, TQP);
  ln_pack_qk_kernel<<<dim3(13, BATCH), 256, 0, stream>>>(k_pool, lnk_w, lnk_b,
                                                         Kh, NKSP, TKP);
  ln_pack_v_kernel<<<dim3(14, BATCH), 256, 0, stream>>>(v_pool, clsv, lnv_w,
                                                        lnv_b, Vht);
  cls_fill_kernel<<<BATCH, 768, 0, stream>>>(clsq, clsk, Qh, Kh);

  // 7. MFMA attention -> o16 (token-major f16, aliases v_lin)
  attn_mfma_kernel<<<dim3(13, NHEADS, BATCH), 256, 0, stream>>>(Qh, Kh, Vht,
                                                                o16);

  // 8. projection MFMA GEMM -> d_out
  float* xo = (float*)d_out;
  float* cls_o = (float*)d_out + (size_t)BATCH * CDIM * NSP;
  gemm_proj_f16_kernel<<<dim3(99, 6), 256, 0, stream>>>(W16p, o16, bproj, xo,
                                                        cls_o);
}

// Round 6
// 641.042 us; speedup vs baseline: 7.0072x; 1.0046x over previous
//
#include <hip/hip_runtime.h>

#define CDIM 768
#define BATCH 8
#define LDEPTH 8
#define HHEIGHT 14
#define WWIDTH 14
#define NSP 1568      // 8*14*14 spatial tokens (input / q)
#define NQTOK 1569    // +cls
#define NKSP 392      // 8*7*7 spatial tokens (k/v after pool)
#define NKTOK 393
#define NHEADS 12
#define HEADDIM 64
#define ATTN_SCALE 0.125f
#define LN_EPS 1e-6f
#define MTOK (BATCH * NQTOK)   // 12552 tokens for proj GEMM
#define NPAD_X 1664            // Xt padded rows per batch (13 tiles * 128)
#define WELEM (CDIM * CDIM)    // 589824
#define TQP 1664               // padded q tokens per (b,h)  (13*128)
#define TKP 448                // padded kv tokens per (b,h) (7*64)
#define LDK 40                 // LDS row stride (f16): 80B = 5 granules, gcd(5,8)=1

typedef _Float16 f16;
typedef _Float16 f16x8_t __attribute__((ext_vector_type(8)));
typedef _Float16 f16x4_t __attribute__((ext_vector_type(4)));
typedef float f32x4_t __attribute__((ext_vector_type(4)));

// ---------------------------------------------------------------------------
// fp32 -> fp16 convert (for weight matrices)
// ---------------------------------------------------------------------------
__global__ __launch_bounds__(256) void convert_f16_kernel(
    const float* __restrict__ src, f16* __restrict__ dst, int n) {
  int i = (blockIdx.x * 256 + threadIdx.x) * 4;
  if (i < n) {
    float4 v = *(const float4*)&src[i];
    f16x4_t h = {(f16)v.x, (f16)v.y, (f16)v.z, (f16)v.w};
    *(f16x4_t*)&dst[i] = h;
  }
}

// ---------------------------------------------------------------------------
// Transpose+convert X: (B,768,1568) f32 -> Xt (B,1664,768) f16, pad rows = 0.
// ---------------------------------------------------------------------------
__global__ __launch_bounds__(256) void transpose_x_kernel(
    const float* __restrict__ X, f16* __restrict__ Xt) {
  __shared__ float t[32][33];
  const int b = blockIdx.z;
  const int k0 = blockIdx.y * 32;
  const int n0 = blockIdx.x * 32;
  const int tx = threadIdx.x & 31, ty = threadIdx.x >> 5;
#pragma unroll
  for (int i = 0; i < 4; i++) {
    int k = k0 + ty + i * 8;
    int n = n0 + tx;
    t[ty + i * 8][tx] = (n < NSP) ? X[((size_t)b * CDIM + k) * NSP + n] : 0.f;
  }
  __syncthreads();
#pragma unroll
  for (int i = 0; i < 4; i++) {
    int n = n0 + ty + i * 8;
    Xt[((size_t)b * NPAD_X + n) * CDIM + k0 + tx] = (f16)t[tx][ty + i * 8];
  }
}

// ---------------------------------------------------------------------------
// Fused QKV MFMA GEMM -> f16 outputs. 1D grid 1872, XCD swizzle: batch = bid&7
// (one batch per XCD -> Xt slice 2.45MB fits 4MB L2). LDS row stride LDK=40
// (2-way bank conflict = free).
// ---------------------------------------------------------------------------
__global__ __launch_bounds__(256) void gemm_qkv_f16_kernel(
    const f16* __restrict__ W16, const f16* __restrict__ Xt,
    const float* __restrict__ bq, const float* __restrict__ bk,
    const float* __restrict__ bv, f16* __restrict__ OutBase) {
  __shared__ __align__(16) f16 Asm[128 * LDK];
  __shared__ __align__(16) f16 Bsm[128 * LDK];

  const int bid = blockIdx.x;
  const int b = bid & 7;          // batch, XCD-contiguous
  const int rem = bid >> 3;       // 0..233
  const int ytile = rem / 13;     // 0..17
  const int n0 = (rem % 13) * 128;
  const int mat = ytile / 6;
  const int m0 = (ytile % 6) * 128;
  const int tid = threadIdx.x;
  const int lane = tid & 63;
  const int w = tid >> 6;
  const int wr = w >> 1, wc = w & 1;
  const int l15 = lane & 15, l4 = lane >> 4;

  const f16* A16 = W16 + (size_t)mat * WELEM;
  const float* bias = (mat == 0) ? bq : (mat == 1) ? bk : bv;
  f16* Out = OutBase + (size_t)mat * ((size_t)BATCH * CDIM * NSP);

  const int r0 = tid >> 2;
  const int kq = (tid & 3) * 8;
  const f16* Ag0 = A16 + (size_t)(m0 + r0) * CDIM + kq;
  const f16* Ag1 = Ag0 + 64 * CDIM;
  const f16* Bg0 = Xt + ((size_t)b * NPAD_X + n0 + r0) * CDIM + kq;
  const f16* Bg1 = Bg0 + 64 * CDIM;

  f32x4_t acc[4][4];
#pragma unroll
  for (int i = 0; i < 4; i++)
#pragma unroll
    for (int j = 0; j < 4; j++) acc[i][j] = (f32x4_t){0.f, 0.f, 0.f, 0.f};

  uint4 ra0 = *(const uint4*)Ag0;
  uint4 ra1 = *(const uint4*)Ag1;
  uint4 rb0 = *(const uint4*)Bg0;
  uint4 rb1 = *(const uint4*)Bg1;

  for (int k0 = 0; k0 < CDIM; k0 += 32) {
    __syncthreads();
    *(uint4*)(Asm + r0 * LDK + kq) = ra0;
    *(uint4*)(Asm + (64 + r0) * LDK + kq) = ra1;
    *(uint4*)(Bsm + r0 * LDK + kq) = rb0;
    *(uint4*)(Bsm + (64 + r0) * LDK + kq) = rb1;
    if (k0 + 32 < CDIM) {
      ra0 = *(const uint4*)(Ag0 + k0 + 32);
      ra1 = *(const uint4*)(Ag1 + k0 + 32);
      rb0 = *(const uint4*)(Bg0 + k0 + 32);
      rb1 = *(const uint4*)(Bg1 + k0 + 32);
    }
    __syncthreads();
    f16x8_t af[4], bf[4];
#pragma unroll
    for (int mi = 0; mi < 4; mi++)
      af[mi] =
          *(const f16x8_t*)(Asm + (wr * 64 + mi * 16 + l15) * LDK + l4 * 8);
#pragma unroll
    for (int ni = 0; ni < 4; ni++)
      bf[ni] =
          *(const f16x8_t*)(Bsm + (wc * 64 + ni * 16 + l15) * LDK + l4 * 8);
#pragma unroll
    for (int mi = 0; mi < 4; mi++)
#pragma unroll
      for (int ni = 0; ni < 4; ni++)
        acc[mi][ni] = __builtin_amdgcn_mfma_f32_16x16x32_f16(
            af[mi], bf[ni], acc[mi][ni], 0, 0, 0);
  }

#pragma unroll
  for (int mi = 0; mi < 4; mi++) {
    const int mbase = m0 + wr * 64 + mi * 16 + l4 * 4;
#pragma unroll
    for (int ni = 0; ni < 4; ni++) {
      const int n = n0 + wc * 64 + ni * 16 + l15;
      if (n < NSP) {
#pragma unroll
        for (int r = 0; r < 4; r++) {
          Out[((size_t)b * CDIM + mbase + r) * NSP + n] =
              (f16)(acc[mi][ni][r] + bias[mbase + r]);
        }
      }
    }
  }
}

// ---------------------------------------------------------------------------
// Projection MFMA GEMM. 1D grid 594, bijective XCD swizzle. LDS stride LDK.
// ---------------------------------------------------------------------------
__global__ __launch_bounds__(256) void gemm_proj_f16_kernel(
    const f16* __restrict__ Wp16, const f16* __restrict__ o16,
    const float* __restrict__ bias, float* __restrict__ xo,
    float* __restrict__ cls_o) {
  __shared__ __align__(16) f16 Asm[128 * LDK];
  __shared__ __align__(16) f16 Bsm[128 * LDK];

  // bijective XCD remap: nwg=594, q=74, r=2
  const int bid = blockIdx.x;
  const int xcd = bid & 7, pos_ = bid >> 3;
  const int base = (xcd < 2) ? xcd * 75 : 150 + (xcd - 2) * 74;
  const int wgid = base + pos_;
  const int m0 = (wgid / 99) * 128;
  const int n0 = (wgid % 99) * 128;
  const int tid = threadIdx.x;
  const int lane = tid & 63;
  const int w = tid >> 6;
  const int wr = w >> 1, wc = w & 1;
  const int l15 = lane & 15, l4 = lane >> 4;

  const int r0 = tid >> 2;
  const int kq = (tid & 3) * 8;
  const f16* Ag0 = Wp16 + (size_t)(m0 + r0) * CDIM + kq;
  const f16* Ag1 = Ag0 + 64 * CDIM;
  const f16* Bg0 = o16 + (size_t)(n0 + r0) * CDIM + kq;
  const f16* Bg1 = Bg0 + 64 * CDIM;

  f32x4_t acc[4][4];
#pragma unroll
  for (int i = 0; i < 4; i++)
#pragma unroll
    for (int j = 0; j < 4; j++) acc[i][j] = (f32x4_t){0.f, 0.f, 0.f, 0.f};

  uint4 ra0 = *(const uint4*)Ag0;
  uint4 ra1 = *(const uint4*)Ag1;
  uint4 rb0 = *(const uint4*)Bg0;
  uint4 rb1 = *(const uint4*)Bg1;

  for (int k0 = 0; k0 < CDIM; k0 += 32) {
    __syncthreads();
    *(uint4*)(Asm + r0 * LDK + kq) = ra0;
    *(uint4*)(Asm + (64 + r0) * LDK + kq) = ra1;
    *(uint4*)(Bsm + r0 * LDK + kq) = rb0;
    *(uint4*)(Bsm + (64 + r0) * LDK + kq) = rb1;
    if (k0 + 32 < CDIM) {
      ra0 = *(const uint4*)(Ag0 + k0 + 32);
      ra1 = *(const uint4*)(Ag1 + k0 + 32);
      rb0 = *(const uint4*)(Bg0 + k0 + 32);
      rb1 = *(const uint4*)(Bg1 + k0 + 32);
    }
    __syncthreads();
    f16x8_t af[4], bf[4];
#pragma unroll
    for (int mi = 0; mi < 4; mi++)
      af[mi] =
          *(const f16x8_t*)(Asm + (wr * 64 + mi * 16 + l15) * LDK + l4 * 8);
#pragma unroll
    for (int ni = 0; ni < 4; ni++)
      bf[ni] =
          *(const f16x8_t*)(Bsm + (wc * 64 + ni * 16 + l15) * LDK + l4 * 8);
#pragma unroll
    for (int mi = 0; mi < 4; mi++)
#pragma unroll
      for (int ni = 0; ni < 4; ni++)
        acc[mi][ni] = __builtin_amdgcn_mfma_f32_16x16x32_f16(
            af[mi], bf[ni], acc[mi][ni], 0, 0, 0);
  }

#pragma unroll
  for (int mi = 0; mi < 4; mi++) {
    const int mbase = m0 + wr * 64 + mi * 16 + l4 * 4;
#pragma unroll
    for (int ni = 0; ni < 4; ni++) {
      const int tok = n0 + wc * 64 + ni * 16 + l15;
      if (tok < MTOK) {
        const int bb = tok / NQTOK;
        const int nn = tok % NQTOK;
#pragma unroll
        for (int r = 0; r < 4; r++) {
          float v = acc[mi][ni][r] + bias[mbase + r];
          if (nn == 0)
            cls_o[bb * CDIM + mbase + r] = v;
          else
            xo[((size_t)bb * CDIM + mbase + r) * (size_t)NSP + nn - 1] = v;
        }
      }
    }
  }
}

// ---------------------------------------------------------------------------
// cls token linear (fp32)
// ---------------------------------------------------------------------------
__global__ __launch_bounds__(256) void cls_linear_kernel(
    const float* __restrict__ cls, const float* __restrict__ W,
    const float* __restrict__ bias, float* __restrict__ out) {
  __shared__ float xs[CDIM];
  const int b = blockIdx.x;
  for (int i = threadIdx.x; i < CDIM; i += 256) xs[i] = cls[b * CDIM + i];
  __syncthreads();
#pragma unroll
  for (int cc = 0; cc < 3; cc++) {
    int co = threadIdx.x + cc * 256;
    const float* wr = W + (size_t)co * CDIM;
    float sum = bias[co];
    for (int k = 0; k < CDIM; k += 4) {
      float4 wv = *(const float4*)&wr[k];
      float4 xv = *(const float4*)&xs[k];
      sum = fmaf(wv.x, xv.x, sum);
      sum = fmaf(wv.y, xv.y, sum);
      sum = fmaf(wv.z, xv.z, sum);
      sum = fmaf(wv.w, xv.w, sum);
    }
    out[b * CDIM + co] = sum;
  }
}

// ---------------------------------------------------------------------------
// Depthwise 3x3x3 conv, f16 in / f16 out (f32 accumulate in LDS + regs).
// ---------------------------------------------------------------------------
__global__ __launch_bounds__(256) void dwconv_kernel(
    const f16* __restrict__ X, const float* __restrict__ wconv,
    f16* __restrict__ Out, int Lo, int Ho, int Wo, int sh, int sw) {
  __shared__ float xin[NSP];
  __shared__ float wsm[27];
  const int c = blockIdx.x % CDIM;
  const int b = blockIdx.x / CDIM;
  const f16* xb = X + ((size_t)b * CDIM + c) * (size_t)NSP;
  for (int i = threadIdx.x * 8; i < NSP; i += 2048) {
    f16x8_t v = *(const f16x8_t*)&xb[i];
#pragma unroll
    for (int j = 0; j < 8; j++) xin[i + j] = (float)v[j];
  }
  if (threadIdx.x < 27) wsm[threadIdx.x] = wconv[c * 27 + threadIdx.x];
  __syncthreads();
  const int npos = Lo * Ho * Wo;
  f16* ob = Out + ((size_t)b * CDIM + c) * (size_t)npos;
  for (int pos = threadIdx.x; pos < npos; pos += 256) {
    int wo = pos % Wo;
    int ho = (pos / Wo) % Ho;
    int lo = pos / (Wo * Ho);
    int li0 = lo - 1, hi0 = ho * sh - 1, wi0 = wo * sw - 1;
    float sum = 0.f;
#pragma unroll
    for (int kd = 0; kd < 3; kd++) {
      int li = li0 + kd;
      if (li < 0 || li >= LDEPTH) continue;
#pragma unroll
      for (int kh = 0; kh < 3; kh++) {
        int hi = hi0 + kh;
        if (hi < 0 || hi >= HHEIGHT) continue;
#pragma unroll
        for (int kw = 0; kw < 3; kw++) {
          int wi = wi0 + kw;
          if (wi < 0 || wi >= WWIDTH) continue;
          sum = fmaf(xin[(li * HHEIGHT + hi) * WWIDTH + wi],
                     wsm[(kd * 3 + kh) * 3 + kw], sum);
        }
      }
    }
    ob[pos] = (f16)sum;
  }
}

// ---------------------------------------------------------------------------
// Fused LayerNorm + head-pack for q/k: read pool (B,768,np) f16, LN over C
// per position, write OutH (B,12,tp,64) f16 at t = pos+1.
// ---------------------------------------------------------------------------
__global__ __launch_bounds__(256) void ln_pack_qk_kernel(
    const f16* __restrict__ xp, const float* __restrict__ ln_w,
    const float* __restrict__ ln_b, f16* __restrict__ OutH, int np, int tp) {
  const int b = blockIdx.y;
  const int p0 = blockIdx.x * 32;
  const int tid = threadIdx.x;
  const int pl = tid & 31;
  const int grp = tid >> 5;
  const int pos = p0 + pl;
  const bool act = pos < np;
  const f16* Xb = xp + (size_t)b * CDIM * (size_t)np;

  __shared__ float r1[8][33], r2[8][33];
  __shared__ float smean[32], srstd[32];
  __shared__ __align__(16) f16 tile[32][72];

  float s1 = 0.f, s2 = 0.f;
  if (act) {
    for (int c = grp; c < CDIM; c += 8) {
      float v = (float)Xb[(size_t)c * np + pos];
      s1 += v;
      s2 = fmaf(v, v, s2);
    }
  }
  r1[grp][pl] = s1;
  r2[grp][pl] = s2;
  __syncthreads();
  if (tid < 32) {
    float t1 = 0.f, t2 = 0.f;
#pragma unroll
    for (int g = 0; g < 8; g++) { t1 += r1[g][tid]; t2 += r2[g][tid]; }
    float mean = t1 * (1.f / 768.f);
    float var = t2 * (1.f / 768.f) - mean * mean;
    smean[tid] = mean;
    srstd[tid] = rsqrtf(var + LN_EPS);
  }
  __syncthreads();
  const float mean = smean[pl], rstd = srstd[pl];
  const int tl = tid >> 3, d8 = (tid & 7) * 8;

  for (int h = 0; h < NHEADS; h++) {
    f16x8_t hv;
#pragma unroll
    for (int i = 0; i < 8; i++) {
      int c = h * 64 + grp * 8 + i;
      float v = act ? (float)Xb[(size_t)c * np + pos] : 0.f;
      hv[i] = (f16)((v - mean) * rstd * ln_w[c] + ln_b[c]);
    }
    *(f16x8_t*)&tile[pl][grp * 8] = hv;
    __syncthreads();
    if (p0 + tl < np) {
      uint4 vv = *(const uint4*)&tile[tl][d8];
      *(uint4*)(OutH +
                (((size_t)(b * NHEADS + h)) * (size_t)tp + (p0 + tl + 1)) * 64 +
                d8) = vv;
    }
    __syncthreads();
  }
}

// ---------------------------------------------------------------------------
// Fused LayerNorm + transpose-pack for v (f16 input).
// ---------------------------------------------------------------------------
__global__ __launch_bounds__(256) void ln_pack_v_kernel(
    const f16* __restrict__ vp, const float* __restrict__ clsv,
    const float* __restrict__ ln_w, const float* __restrict__ ln_b,
    f16* __restrict__ Vht) {
  const int b = blockIdx.y;
  const int t0 = blockIdx.x * 32;
  const int tid = threadIdx.x;
  const int pl = tid & 31;
  const int grp = tid >> 5;
  const int t = t0 + pl;
  const int pos = t - 1;
  const bool isv = (t >= 1) && (t < NKTOK);
  const f16* Vb = vp + (size_t)b * CDIM * (size_t)NKSP;

  __shared__ float r1[8][33], r2[8][33];
  __shared__ float smean[32], srstd[32];
  __shared__ __align__(16) f16 vtile[128][40];

  float s1 = 0.f, s2 = 0.f;
  if (isv) {
    for (int c = grp; c < CDIM; c += 8) {
      float v = (float)Vb[(size_t)c * NKSP + pos];
      s1 += v;
      s2 = fmaf(v, v, s2);
    }
  }
  r1[grp][pl] = s1;
  r2[grp][pl] = s2;
  __syncthreads();
  if (tid < 32) {
    float t1 = 0.f, t2 = 0.f;
#pragma unroll
    for (int g = 0; g < 8; g++) { t1 += r1[g][tid]; t2 += r2[g][tid]; }
    float mean = t1 * (1.f / 768.f);
    float var = t2 * (1.f / 768.f) - mean * mean;
    smean[tid] = mean;
    srstd[tid] = rsqrtf(var + LN_EPS);
  }
  __syncthreads();
  const float mean = smean[pl], rstd = srstd[pl];

  for (int cc = 0; cc < 6; cc++) {
#pragma unroll
    for (int i = 0; i < 16; i++) {
      int cl = grp * 16 + i;
      int c = cc * 128 + cl;
      float outv;
      if (isv)
        outv = ((float)Vb[(size_t)c * NKSP + pos] - mean) * rstd * ln_w[c] +
               ln_b[c];
      else if (t == 0)
        outv = clsv[b * CDIM + c];
      else
        outv = 0.f;
      vtile[cl][pl] = (f16)outv;
    }
    __syncthreads();
#pragma unroll
    for (int it = 0; it < 2; it++) {
      int idx = it * 256 + tid;
      int cl = idx >> 2, t8 = (idx & 3) * 8;
      uint4 vv = *(const uint4*)&vtile[cl][t8];
      *(uint4*)(Vht + ((size_t)b * CDIM + cc * 128 + cl) * (size_t)TKP + t0 +
                t8) = vv;
    }
    __syncthreads();
  }
}

// ---------------------------------------------------------------------------
// cls_fill: write t=0 rows of Qh and Kh from cls linear outputs.
// ---------------------------------------------------------------------------
__global__ __launch_bounds__(768) void cls_fill_kernel(
    const float* __restrict__ clsq, const float* __restrict__ clsk,
    f16* __restrict__ Qh, f16* __restrict__ Kh) {
  const int b = blockIdx.x;
  const int c = threadIdx.x;
  Qh[(((size_t)(b * NHEADS + (c >> 6))) * TQP) * 64 + (c & 63)] =
      (f16)clsq[b * CDIM + c];
  Kh[(((size_t)(b * NHEADS + (c >> 6))) * TKP) * 64 + (c & 63)] =
      (f16)clsk[b * CDIM + c];
}

// ---------------------------------------------------------------------------
// MFMA flash attention. Grid (13, 12, 8), 256 threads = 4 waves.
// ---------------------------------------------------------------------------
__global__ __launch_bounds__(256) void attn_mfma_kernel(
    const f16* __restrict__ Qh, const f16* __restrict__ Kh,
    const f16* __restrict__ Vht, f16* __restrict__ o16) {
  __shared__ __align__(16) f16 Ks[64 * 72];   // [key][d], pad 8
  __shared__ __align__(16) f16 Vt[64 * 72];   // [d][key], pad 8
  const int qt = blockIdx.x, h = blockIdx.y, b = blockIdx.z;
  const int tid = threadIdx.x;
  const int lane = tid & 63;
  const int w = tid >> 6;
  const int l15 = lane & 15, l4 = lane >> 4;
  const int q0 = qt * 128 + w * 32;

  const f16* Qp = Qh + ((size_t)(b * NHEADS + h) * TQP) * 64;
  const f16* Kp = Kh + ((size_t)(b * NHEADS + h) * TKP) * 64;
  const f16* Vp = Vht + ((size_t)(b * NHEADS + h) * 64) * TKP;

  f16x8_t bq[2][2];
#pragma unroll
  for (int qi = 0; qi < 2; qi++)
#pragma unroll
    for (int kf = 0; kf < 2; kf++)
      bq[qi][kf] = *(const f16x8_t*)(Qp + (size_t)(q0 + qi * 16 + l15) * 64 +
                                     kf * 32 + l4 * 8);

  f32x4_t oacc[4][2];
#pragma unroll
  for (int df = 0; df < 4; df++)
#pragma unroll
    for (int qi = 0; qi < 2; qi++) oacc[df][qi] = (f32x4_t){0.f, 0.f, 0.f, 0.f};
  float mrow[2] = {-1e30f, -1e30f};
  float lrow[2] = {0.f, 0.f};

  const int sr = tid >> 2, sc = (tid & 3) * 16;

  for (int kv0 = 0; kv0 < TKP; kv0 += 64) {
    const f16* kg = Kp + (size_t)(kv0 + sr) * 64 + sc;
    uint4 kl0 = *(const uint4*)kg;
    uint4 kl1 = *(const uint4*)(kg + 8);
    const f16* vg = Vp + (size_t)sr * TKP + kv0 + sc;
    uint4 vl0 = *(const uint4*)vg;
    uint4 vl1 = *(const uint4*)(vg + 8);
    __syncthreads();
    *(uint4*)(Ks + sr * 72 + sc) = kl0;
    *(uint4*)(Ks + sr * 72 + sc + 8) = kl1;
    *(uint4*)(Vt + sr * 72 + sc) = vl0;
    *(uint4*)(Vt + sr * 72 + sc + 8) = vl1;
    __syncthreads();

    f32x4_t sacc[4][2];
#pragma unroll
    for (int ki = 0; ki < 4; ki++)
#pragma unroll
      for (int qi = 0; qi < 2; qi++) sacc[ki][qi] = (f32x4_t){0.f, 0.f, 0.f, 0.f};
#pragma unroll
    for (int kf = 0; kf < 2; kf++) {
#pragma unroll
      for (int ki = 0; ki < 4; ki++) {
        f16x8_t ak =
            *(const f16x8_t*)(Ks + (ki * 16 + l15) * 72 + kf * 32 + l4 * 8);
#pragma unroll
        for (int qi = 0; qi < 2; qi++)
          sacc[ki][qi] = __builtin_amdgcn_mfma_f32_16x16x32_f16(
              ak, bq[qi][kf], sacc[ki][qi], 0, 0, 0);
      }
    }

    float pmax[2] = {-1e30f, -1e30f};
#pragma unroll
    for (int ki = 0; ki < 4; ki++) {
      const int keyb = kv0 + ki * 16 + l4 * 4;
#pragma unroll
      for (int qi = 0; qi < 2; qi++) {
#pragma unroll
        for (int rr = 0; rr < 4; rr++) {
          float s = sacc[ki][qi][rr] * ATTN_SCALE;
          if (keyb + rr >= NKTOK) s = -1e30f;
          sacc[ki][qi][rr] = s;
          pmax[qi] = fmaxf(pmax[qi], s);
        }
      }
    }
#pragma unroll
    for (int qi = 0; qi < 2; qi++) {
      pmax[qi] = fmaxf(pmax[qi], __shfl_xor(pmax[qi], 16, 64));
      pmax[qi] = fmaxf(pmax[qi], __shfl_xor(pmax[qi], 32, 64));
      float mnew = fmaxf(mrow[qi], pmax[qi]);
      float alpha = __expf(mrow[qi] - mnew);
      mrow[qi] = mnew;
      lrow[qi] *= alpha;
#pragma unroll
      for (int df = 0; df < 4; df++) {
        oacc[df][qi][0] *= alpha;
        oacc[df][qi][1] *= alpha;
        oacc[df][qi][2] *= alpha;
        oacc[df][qi][3] *= alpha;
      }
    }
    f16x4_t pb[4][2];
#pragma unroll
    for (int ki = 0; ki < 4; ki++) {
#pragma unroll
      for (int qi = 0; qi < 2; qi++) {
        float p0 = __expf(sacc[ki][qi][0] - mrow[qi]);
        float p1 = __expf(sacc[ki][qi][1] - mrow[qi]);
        float p2 = __expf(sacc[ki][qi][2] - mrow[qi]);
        float p3 = __expf(sacc[ki][qi][3] - mrow[qi]);
        lrow[qi] += p0 + p1 + p2 + p3;
        f16x4_t pv = {(f16)p0, (f16)p1, (f16)p2, (f16)p3};
        pb[ki][qi] = pv;
      }
    }

#pragma unroll
    for (int df = 0; df < 4; df++) {
#pragma unroll
      for (int ki = 0; ki < 4; ki++) {
        f16x4_t av =
            *(const f16x4_t*)(Vt + (df * 16 + l15) * 72 + ki * 16 + l4 * 4);
#pragma unroll
        for (int qi = 0; qi < 2; qi++)
          oacc[df][qi] = __builtin_amdgcn_mfma_f32_16x16x16f16(
              av, pb[ki][qi], oacc[df][qi], 0, 0, 0);
      }
    }
  }

  float inv[2];
#pragma unroll
  for (int qi = 0; qi < 2; qi++) {
    float l = lrow[qi];
    l += __shfl_xor(l, 16, 64);
    l += __shfl_xor(l, 32, 64);
    inv[qi] = 1.f / l;
  }
#pragma unroll
  for (int qi = 0; qi < 2; qi++) {
    const int q = q0 + qi * 16 + l15;
    if (q < NQTOK) {
      f16* op = o16 + ((size_t)(b * NQTOK + q)) * CDIM + h * 64 + l4 * 4;
#pragma unroll
      for (int df = 0; df < 4; df++) {
        f16x4_t ov = {(f16)(oacc[df][qi][0] * inv[qi]),
                      (f16)(oacc[df][qi][1] * inv[qi]),
                      (f16)(oacc[df][qi][2] * inv[qi]),
                      (f16)(oacc[df][qi][3] * inv[qi])};
        *(f16x4_t*)(op + df * 16) = ov;
      }
    }
  }
}

// ---------------------------------------------------------------------------
extern "C" void kernel_launch(void* const* d_in, const int* in_sizes, int n_in,
                              void* d_out, int out_size, void* d_ws, size_t ws_size,
                              hipStream_t stream) {
  const float* x      = (const float*)d_in[0];
  const float* cls    = (const float*)d_in[1];
  const float* Wq     = (const float*)d_in[2];
  const float* bq     = (const float*)d_in[3];
  const float* Wk     = (const float*)d_in[4];
  const float* bk     = (const float*)d_in[5];
  const float* Wv     = (const float*)d_in[6];
  const float* bv     = (const float*)d_in[7];
  const float* conv_q = (const float*)d_in[8];
  const float* conv_k = (const float*)d_in[9];
  const float* conv_v = (const float*)d_in[10];
  const float* lnq_w  = (const float*)d_in[11];
  const float* lnq_b  = (const float*)d_in[12];
  const float* lnk_w  = (const float*)d_in[13];
  const float* lnk_b  = (const float*)d_in[14];
  const float* lnv_w  = (const float*)d_in[15];
  const float* lnv_b  = (const float*)d_in[16];
  const float* Wproj  = (const float*)d_in[17];
  const float* bproj  = (const float*)d_in[18];

  // Workspace layout (bytes), all f16 intermediates. Total ≈ 103.7 MB.
  char* wsb = (char*)d_ws;
  f16*   Xt     = (f16*)(wsb + 0);           // 20,447,232
  f16*   W16    = (f16*)(wsb + 20447232);    //  4,718,592
  f16*   q_lin  = (f16*)(wsb + 25165824);    // 19,267,584
  f16*   k_lin  = (f16*)(wsb + 44433408);    // 19,267,584
  f16*   v_lin  = (f16*)(wsb + 63700992);    // 19,267,584
  f16*   k_pool = (f16*)(wsb + 82968576);    //  4,816,896
  f16*   v_pool = (f16*)(wsb + 87785472);    //  4,816,896
  float* clsq   = (float*)(wsb + 92602368);  //     24,576
  float* clsk   = (float*)(wsb + 92626944);
  float* clsv   = (float*)(wsb + 92651520);
  f16*   Kh     = (f16*)(wsb + 92676096);    //  5,505,024
  f16*   Vht    = (f16*)(wsb + 98181120);    //  5,505,024 -> end 103,686,144
  f16*   q_pool = k_lin;        // alias: k_lin dead after dwconv_k (same size)
  f16*   Qh     = Xt;           // alias: Xt dead after QKV GEMM (same size)
  f16*   o16    = v_lin;        // alias: v_lin + start of k_pool (both dead
                                // by attention); needs 19,464,192 B

  f16* W16q = W16;
  f16* W16k = W16 + (size_t)WELEM;
  f16* W16v = W16 + (size_t)2 * WELEM;
  f16* W16p = W16 + (size_t)3 * WELEM;

  // 1. convert weights to fp16
  convert_f16_kernel<<<576, 256, 0, stream>>>(Wq, W16q, WELEM);
  convert_f16_kernel<<<576, 256, 0, stream>>>(Wk, W16k, WELEM);
  convert_f16_kernel<<<576, 256, 0, stream>>>(Wv, W16v, WELEM);
  convert_f16_kernel<<<576, 256, 0, stream>>>(Wproj, W16p, WELEM);

  // 2. transpose+convert X -> Xt
  transpose_x_kernel<<<dim3(52, 24, BATCH), 256, 0, stream>>>(x, Xt);

  // 3. fused QKV MFMA GEMM (1D grid, XCD-batch swizzle) -> f16 lin buffers
  gemm_qkv_f16_kernel<<<1872, 256, 0, stream>>>(W16, Xt, bq, bk, bv, q_lin);

  // 4. cls token linears
  cls_linear_kernel<<<BATCH, 256, 0, stream>>>(cls, Wq, bq, clsq);
  cls_linear_kernel<<<BATCH, 256, 0, stream>>>(cls, Wk, bk, clsk);
  cls_linear_kernel<<<BATCH, 256, 0, stream>>>(cls, Wv, bv, clsv);

  // 5. depthwise convs (k first, then q overwrites k_lin via alias)
  dwconv_kernel<<<BATCH * CDIM, 256, 0, stream>>>(k_lin, conv_k, k_pool,
                                                  8, 7, 7, 2, 2);
  dwconv_kernel<<<BATCH * CDIM, 256, 0, stream>>>(v_lin, conv_v, v_pool,
                                                  8, 7, 7, 2, 2);
  dwconv_kernel<<<BATCH * CDIM, 256, 0, stream>>>(q_lin, conv_q, q_pool,
                                                  8, 14, 14, 1, 1);

  // 6. fused LN + pack
  ln_pack_qk_kernel<<<dim3(49, BATCH), 256, 0, stream>>>(q_pool, lnq_w, lnq_b,
                                                         Qh, NSP, TQP);
  ln_pack_qk_kernel<<<dim3(13, BATCH), 256, 0, stream>>>(k_pool, lnk_w, lnk_b,
                                                         Kh, NKSP, TKP);
  ln_pack_v_kernel<<<dim3(14, BATCH), 256, 0, stream>>>(v_pool, clsv, lnv_w,
                                                        lnv_b, Vht);
  cls_fill_kernel<<<BATCH, 768, 0, stream>>>(clsq, clsk, Qh, Kh);

  // 7. MFMA attention -> o16
  attn_mfma_kernel<<<dim3(13, NHEADS, BATCH), 256, 0, stream>>>(Qh, Kh, Vht,
                                                                o16);

  // 8. projection MFMA GEMM (bijective XCD swizzle) -> d_out
  float* xo = (float*)d_out;
  float* cls_o = (float*)d_out + (size_t)BATCH * CDIM * NSP;
  gemm_proj_f16_kernel<<<594, 256, 0, stream>>>(W16p, o16, bproj, xo, cls_o);
}

// Round 7
// 483.822 us; speedup vs baseline: 9.2843x; 1.3250x over previous
//
#include <hip/hip_runtime.h>

#define CDIM 768
#define BATCH 8
#define LDEPTH 8
#define HHEIGHT 14
#define WWIDTH 14
#define NSP 1568      // 8*14*14 spatial tokens (input / q)
#define NQTOK 1569    // +cls
#define NKSP 392      // 8*7*7 spatial tokens (k/v after pool)
#define NKTOK 393
#define NHEADS 12
#define HEADDIM 64
#define ATTN_SCALE 0.125f
#define LN_EPS 1e-6f
#define MTOK (BATCH * NQTOK)   // 12552 tokens for proj GEMM
#define NPAD_X 1664            // Xt padded rows per batch (13 tiles * 128)
#define WELEM (CDIM * CDIM)    // 589824
#define TQP 1664               // padded q tokens per (b,h)  (13*128)
#define TKP 448                // padded kv tokens per (b,h) (7*64)

typedef _Float16 f16;
typedef _Float16 f16x8_t __attribute__((ext_vector_type(8)));
typedef _Float16 f16x4_t __attribute__((ext_vector_type(4)));
typedef float f32x4_t __attribute__((ext_vector_type(4)));

// global -> LDS direct 16B copy (wave-uniform LDS base + lane*16)
__device__ __forceinline__ void gld_lds16(const void* g, void* l) {
  __builtin_amdgcn_global_load_lds(
      (const __attribute__((address_space(1))) void*)g,
      (__attribute__((address_space(3))) void*)l, 16, 0, 0);
}

// ---------------------------------------------------------------------------
// fp32 -> fp16 convert for the 4 weight matrices (one launch, grid.y = mat)
// ---------------------------------------------------------------------------
__global__ __launch_bounds__(256) void convert4_kernel(
    const float* __restrict__ s0, const float* __restrict__ s1,
    const float* __restrict__ s2, const float* __restrict__ s3,
    f16* __restrict__ dst) {
  const int mat = blockIdx.y;
  const float* src = (mat == 0) ? s0 : (mat == 1) ? s1 : (mat == 2) ? s2 : s3;
  int i = (blockIdx.x * 256 + threadIdx.x) * 4;
  if (i < WELEM) {
    float4 v = *(const float4*)&src[i];
    f16x4_t h = {(f16)v.x, (f16)v.y, (f16)v.z, (f16)v.w};
    *(f16x4_t*)&dst[(size_t)mat * WELEM + i] = h;
  }
}

// ---------------------------------------------------------------------------
// Transpose+convert X: (B,768,1568) f32 -> Xt (B,1664,768) f16, pad rows = 0.
// ---------------------------------------------------------------------------
__global__ __launch_bounds__(256) void transpose_x_kernel(
    const float* __restrict__ X, f16* __restrict__ Xt) {
  __shared__ float t[32][33];
  const int b = blockIdx.z;
  const int k0 = blockIdx.y * 32;
  const int n0 = blockIdx.x * 32;
  const int tx = threadIdx.x & 31, ty = threadIdx.x >> 5;
#pragma unroll
  for (int i = 0; i < 4; i++) {
    int k = k0 + ty + i * 8;
    int n = n0 + tx;
    t[ty + i * 8][tx] = (n < NSP) ? X[((size_t)b * CDIM + k) * NSP + n] : 0.f;
  }
  __syncthreads();
#pragma unroll
  for (int i = 0; i < 4; i++) {
    int n = n0 + ty + i * 8;
    Xt[((size_t)b * NPAD_X + n) * CDIM + k0 + tx] = (f16)t[tx][ty + i * 8];
  }
}

// ---------------------------------------------------------------------------
// Fused QKV MFMA GEMM, global_load_lds staging (linear [128][32] LDS tiles).
// 1D grid 1872, XCD swizzle: batch = bid&7. Single-buffer, 2 barriers/K-step.
// ---------------------------------------------------------------------------
__global__ __launch_bounds__(256) void gemm_qkv_f16_kernel(
    const f16* __restrict__ W16, const f16* __restrict__ Xt,
    const float* __restrict__ bq, const float* __restrict__ bk,
    const float* __restrict__ bv, f16* __restrict__ OutBase) {
  __shared__ __align__(16) f16 Asm[128 * 32];
  __shared__ __align__(16) f16 Bsm[128 * 32];

  const int bid = blockIdx.x;
  const int b = bid & 7;          // batch, XCD-contiguous
  const int rem = bid >> 3;       // 0..233
  const int ytile = rem / 13;     // 0..17
  const int n0 = (rem % 13) * 128;
  const int mat = ytile / 6;
  const int m0 = (ytile % 6) * 128;
  const int tid = threadIdx.x;
  const int lane = tid & 63;
  const int w = tid >> 6;
  const int wr = w >> 1, wc = w & 1;
  const int l15 = lane & 15, l4 = lane >> 4;

  const f16* A16 = W16 + (size_t)mat * WELEM;
  const float* bias = (mat == 0) ? bq : (mat == 1) ? bk : bv;
  f16* Out = OutBase + (size_t)mat * ((size_t)BATCH * CDIM * NSP);

  // staging: wave w covers rows [w*32, w*32+32); lane -> row w*32 + (lane>>2),
  // k-chunk (lane&3)*8. Two instrs per operand (rows +0 / +16).
  const int srow = w * 32 + (lane >> 2);
  const int skq = (lane & 3) * 8;
  const f16* Ag = A16 + (size_t)(m0 + srow) * CDIM + skq;
  const f16* Bg = Xt + ((size_t)b * NPAD_X + n0 + srow) * CDIM + skq;
  f16* lA = Asm + w * 32 * 32;
  f16* lB = Bsm + w * 32 * 32;

  f32x4_t acc[4][4];
#pragma unroll
  for (int i = 0; i < 4; i++)
#pragma unroll
    for (int j = 0; j < 4; j++) acc[i][j] = (f32x4_t){0.f, 0.f, 0.f, 0.f};

  for (int k0 = 0; k0 < CDIM; k0 += 32) {
    gld_lds16(Ag + k0, lA);
    gld_lds16(Ag + 16 * CDIM + k0, lA + 16 * 32);
    gld_lds16(Bg + k0, lB);
    gld_lds16(Bg + 16 * CDIM + k0, lB + 16 * 32);
    __syncthreads();   // compiler drains vmcnt here
    f16x8_t af[4], bf[4];
#pragma unroll
    for (int mi = 0; mi < 4; mi++)
      af[mi] = *(const f16x8_t*)(Asm + (wr * 64 + mi * 16 + l15) * 32 + l4 * 8);
#pragma unroll
    for (int ni = 0; ni < 4; ni++)
      bf[ni] = *(const f16x8_t*)(Bsm + (wc * 64 + ni * 16 + l15) * 32 + l4 * 8);
#pragma unroll
    for (int mi = 0; mi < 4; mi++)
#pragma unroll
      for (int ni = 0; ni < 4; ni++)
        acc[mi][ni] = __builtin_amdgcn_mfma_f32_16x16x32_f16(
            af[mi], bf[ni], acc[mi][ni], 0, 0, 0);
    __syncthreads();   // all reads done before next overwrite
  }

#pragma unroll
  for (int mi = 0; mi < 4; mi++) {
    const int mbase = m0 + wr * 64 + mi * 16 + l4 * 4;
#pragma unroll
    for (int ni = 0; ni < 4; ni++) {
      const int n = n0 + wc * 64 + ni * 16 + l15;
      if (n < NSP) {
#pragma unroll
        for (int r = 0; r < 4; r++) {
          Out[((size_t)b * CDIM + mbase + r) * NSP + n] =
              (f16)(acc[mi][ni][r] + bias[mbase + r]);
        }
      }
    }
  }
}

// ---------------------------------------------------------------------------
// Projection MFMA GEMM, global_load_lds staging. 1D grid 594, bijective XCD
// swizzle.
// ---------------------------------------------------------------------------
__global__ __launch_bounds__(256) void gemm_proj_f16_kernel(
    const f16* __restrict__ Wp16, const f16* __restrict__ o16,
    const float* __restrict__ bias, float* __restrict__ xo,
    float* __restrict__ cls_o) {
  __shared__ __align__(16) f16 Asm[128 * 32];
  __shared__ __align__(16) f16 Bsm[128 * 32];

  // bijective XCD remap: nwg=594, q=74, r=2
  const int bid = blockIdx.x;
  const int xcd = bid & 7, pos_ = bid >> 3;
  const int base = (xcd < 2) ? xcd * 75 : 150 + (xcd - 2) * 74;
  const int wgid = base + pos_;
  const int m0 = (wgid / 99) * 128;
  const int n0 = (wgid % 99) * 128;
  const int tid = threadIdx.x;
  const int lane = tid & 63;
  const int w = tid >> 6;
  const int wr = w >> 1, wc = w & 1;
  const int l15 = lane & 15, l4 = lane >> 4;

  const int srow = w * 32 + (lane >> 2);
  const int skq = (lane & 3) * 8;
  const f16* Ag = Wp16 + (size_t)(m0 + srow) * CDIM + skq;
  const f16* Bg = o16 + (size_t)(n0 + srow) * CDIM + skq;
  f16* lA = Asm + w * 32 * 32;
  f16* lB = Bsm + w * 32 * 32;

  f32x4_t acc[4][4];
#pragma unroll
  for (int i = 0; i < 4; i++)
#pragma unroll
    for (int j = 0; j < 4; j++) acc[i][j] = (f32x4_t){0.f, 0.f, 0.f, 0.f};

  for (int k0 = 0; k0 < CDIM; k0 += 32) {
    gld_lds16(Ag + k0, lA);
    gld_lds16(Ag + 16 * CDIM + k0, lA + 16 * 32);
    gld_lds16(Bg + k0, lB);
    gld_lds16(Bg + 16 * CDIM + k0, lB + 16 * 32);
    __syncthreads();
    f16x8_t af[4], bf[4];
#pragma unroll
    for (int mi = 0; mi < 4; mi++)
      af[mi] = *(const f16x8_t*)(Asm + (wr * 64 + mi * 16 + l15) * 32 + l4 * 8);
#pragma unroll
    for (int ni = 0; ni < 4; ni++)
      bf[ni] = *(const f16x8_t*)(Bsm + (wc * 64 + ni * 16 + l15) * 32 + l4 * 8);
#pragma unroll
    for (int mi = 0; mi < 4; mi++)
#pragma unroll
      for (int ni = 0; ni < 4; ni++)
        acc[mi][ni] = __builtin_amdgcn_mfma_f32_16x16x32_f16(
            af[mi], bf[ni], acc[mi][ni], 0, 0, 0);
    __syncthreads();
  }

#pragma unroll
  for (int ni = 0; ni < 4; ni++) {
    const int tok = n0 + wc * 64 + ni * 16 + l15;
    if (tok < MTOK) {
      const int bb = tok / NQTOK;
      const int nn = tok % NQTOK;
#pragma unroll
      for (int mi = 0; mi < 4; mi++) {
        const int mbase = m0 + wr * 64 + mi * 16 + l4 * 4;
#pragma unroll
        for (int r = 0; r < 4; r++) {
          float v = acc[mi][ni][r] + bias[mbase + r];
          if (nn == 0)
            cls_o[bb * CDIM + mbase + r] = v;
          else
            xo[((size_t)bb * CDIM + mbase + r) * (size_t)NSP + nn - 1] = v;
        }
      }
    }
  }
}

// ---------------------------------------------------------------------------
// cls token linears (fp32), one launch: grid (B, 3)
// ---------------------------------------------------------------------------
__global__ __launch_bounds__(256) void cls_linear3_kernel(
    const float* __restrict__ cls, const float* __restrict__ Wq,
    const float* __restrict__ Wk, const float* __restrict__ Wv,
    const float* __restrict__ bq, const float* __restrict__ bk,
    const float* __restrict__ bv, float* __restrict__ out_base) {
  __shared__ float xs[CDIM];
  const int b = blockIdx.x;
  const int mat = blockIdx.y;
  const float* W = (mat == 0) ? Wq : (mat == 1) ? Wk : Wv;
  const float* bias = (mat == 0) ? bq : (mat == 1) ? bk : bv;
  float* out = out_base + (size_t)mat * BATCH * CDIM;
  for (int i = threadIdx.x; i < CDIM; i += 256) xs[i] = cls[b * CDIM + i];
  __syncthreads();
#pragma unroll
  for (int cc = 0; cc < 3; cc++) {
    int co = threadIdx.x + cc * 256;
    const float* wr = W + (size_t)co * CDIM;
    float sum = bias[co];
    for (int k = 0; k < CDIM; k += 4) {
      float4 wv = *(const float4*)&wr[k];
      float4 xv = *(const float4*)&xs[k];
      sum = fmaf(wv.x, xv.x, sum);
      sum = fmaf(wv.y, xv.y, sum);
      sum = fmaf(wv.z, xv.z, sum);
      sum = fmaf(wv.w, xv.w, sum);
    }
    out[b * CDIM + co] = sum;
  }
}

// ---------------------------------------------------------------------------
// Depthwise 3x3x3 conv, f16 in / f16 out (f32 accumulate).
// ---------------------------------------------------------------------------
__global__ __launch_bounds__(256) void dwconv_kernel(
    const f16* __restrict__ X, const float* __restrict__ wconv,
    f16* __restrict__ Out, int Lo, int Ho, int Wo, int sh, int sw) {
  __shared__ float xin[NSP];
  __shared__ float wsm[27];
  const int c = blockIdx.x % CDIM;
  const int b = blockIdx.x / CDIM;
  const f16* xb = X + ((size_t)b * CDIM + c) * (size_t)NSP;
  for (int i = threadIdx.x * 8; i < NSP; i += 2048) {
    f16x8_t v = *(const f16x8_t*)&xb[i];
#pragma unroll
    for (int j = 0; j < 8; j++) xin[i + j] = (float)v[j];
  }
  if (threadIdx.x < 27) wsm[threadIdx.x] = wconv[c * 27 + threadIdx.x];
  __syncthreads();
  const int npos = Lo * Ho * Wo;
  f16* ob = Out + ((size_t)b * CDIM + c) * (size_t)npos;
  for (int pos = threadIdx.x; pos < npos; pos += 256) {
    int wo = pos % Wo;
    int ho = (pos / Wo) % Ho;
    int lo = pos / (Wo * Ho);
    int li0 = lo - 1, hi0 = ho * sh - 1, wi0 = wo * sw - 1;
    float sum = 0.f;
#pragma unroll
    for (int kd = 0; kd < 3; kd++) {
      int li = li0 + kd;
      if (li < 0 || li >= LDEPTH) continue;
#pragma unroll
      for (int kh = 0; kh < 3; kh++) {
        int hi = hi0 + kh;
        if (hi < 0 || hi >= HHEIGHT) continue;
#pragma unroll
        for (int kw = 0; kw < 3; kw++) {
          int wi = wi0 + kw;
          if (wi < 0 || wi >= WWIDTH) continue;
          sum = fmaf(xin[(li * HHEIGHT + hi) * WWIDTH + wi],
                     wsm[(kd * 3 + kh) * 3 + kw], sum);
        }
      }
    }
    ob[pos] = (f16)sum;
  }
}

// ---------------------------------------------------------------------------
// Fused LayerNorm + head-pack for q/k (f16 in, f16 head layout out).
// ---------------------------------------------------------------------------
__global__ __launch_bounds__(256) void ln_pack_qk_kernel(
    const f16* __restrict__ xp, const float* __restrict__ ln_w,
    const float* __restrict__ ln_b, f16* __restrict__ OutH, int np, int tp) {
  const int b = blockIdx.y;
  const int p0 = blockIdx.x * 32;
  const int tid = threadIdx.x;
  const int pl = tid & 31;
  const int grp = tid >> 5;
  const int pos = p0 + pl;
  const bool act = pos < np;
  const f16* Xb = xp + (size_t)b * CDIM * (size_t)np;

  __shared__ float r1[8][33], r2[8][33];
  __shared__ float smean[32], srstd[32];
  __shared__ __align__(16) f16 tile[32][72];

  float s1 = 0.f, s2 = 0.f;
  if (act) {
    for (int c = grp; c < CDIM; c += 8) {
      float v = (float)Xb[(size_t)c * np + pos];
      s1 += v;
      s2 = fmaf(v, v, s2);
    }
  }
  r1[grp][pl] = s1;
  r2[grp][pl] = s2;
  __syncthreads();
  if (tid < 32) {
    float t1 = 0.f, t2 = 0.f;
#pragma unroll
    for (int g = 0; g < 8; g++) { t1 += r1[g][tid]; t2 += r2[g][tid]; }
    float mean = t1 * (1.f / 768.f);
    float var = t2 * (1.f / 768.f) - mean * mean;
    smean[tid] = mean;
    srstd[tid] = rsqrtf(var + LN_EPS);
  }
  __syncthreads();
  const float mean = smean[pl], rstd = srstd[pl];
  const int tl = tid >> 3, d8 = (tid & 7) * 8;

  for (int h = 0; h < NHEADS; h++) {
    f16x8_t hv;
#pragma unroll
    for (int i = 0; i < 8; i++) {
      int c = h * 64 + grp * 8 + i;
      float v = act ? (float)Xb[(size_t)c * np + pos] : 0.f;
      hv[i] = (f16)((v - mean) * rstd * ln_w[c] + ln_b[c]);
    }
    *(f16x8_t*)&tile[pl][grp * 8] = hv;
    __syncthreads();
    if (p0 + tl < np) {
      uint4 vv = *(const uint4*)&tile[tl][d8];
      *(uint4*)(OutH +
                (((size_t)(b * NHEADS + h)) * (size_t)tp + (p0 + tl + 1)) * 64 +
                d8) = vv;
    }
    __syncthreads();
  }
}

// ---------------------------------------------------------------------------
// Fused LayerNorm + transpose-pack for v (f16 input).
// ---------------------------------------------------------------------------
__global__ __launch_bounds__(256) void ln_pack_v_kernel(
    const f16* __restrict__ vp, const float* __restrict__ clsv,
    const float* __restrict__ ln_w, const float* __restrict__ ln_b,
    f16* __restrict__ Vht) {
  const int b = blockIdx.y;
  const int t0 = blockIdx.x * 32;
  const int tid = threadIdx.x;
  const int pl = tid & 31;
  const int grp = tid >> 5;
  const int t = t0 + pl;
  const int pos = t - 1;
  const bool isv = (t >= 1) && (t < NKTOK);
  const f16* Vb = vp + (size_t)b * CDIM * (size_t)NKSP;

  __shared__ float r1[8][33], r2[8][33];
  __shared__ float smean[32], srstd[32];
  __shared__ __align__(16) f16 vtile[128][40];

  float s1 = 0.f, s2 = 0.f;
  if (isv) {
    for (int c = grp; c < CDIM; c += 8) {
      float v = (float)Vb[(size_t)c * NKSP + pos];
      s1 += v;
      s2 = fmaf(v, v, s2);
    }
  }
  r1[grp][pl] = s1;
  r2[grp][pl] = s2;
  __syncthreads();
  if (tid < 32) {
    float t1 = 0.f, t2 = 0.f;
#pragma unroll
    for (int g = 0; g < 8; g++) { t1 += r1[g][tid]; t2 += r2[g][tid]; }
    float mean = t1 * (1.f / 768.f);
    float var = t2 * (1.f / 768.f) - mean * mean;
    smean[tid] = mean;
    srstd[tid] = rsqrtf(var + LN_EPS);
  }
  __syncthreads();
  const float mean = smean[pl], rstd = srstd[pl];

  for (int cc = 0; cc < 6; cc++) {
#pragma unroll
    for (int i = 0; i < 16; i++) {
      int cl = grp * 16 + i;
      int c = cc * 128 + cl;
      float outv;
      if (isv)
        outv = ((float)Vb[(size_t)c * NKSP + pos] - mean) * rstd * ln_w[c] +
               ln_b[c];
      else if (t == 0)
        outv = clsv[b * CDIM + c];
      else
        outv = 0.f;
      vtile[cl][pl] = (f16)outv;
    }
    __syncthreads();
#pragma unroll
    for (int it = 0; it < 2; it++) {
      int idx = it * 256 + tid;
      int cl = idx >> 2, t8 = (idx & 3) * 8;
      uint4 vv = *(const uint4*)&vtile[cl][t8];
      *(uint4*)(Vht + ((size_t)b * CDIM + cc * 128 + cl) * (size_t)TKP + t0 +
                t8) = vv;
    }
    __syncthreads();
  }
}

// ---------------------------------------------------------------------------
// cls_fill: write t=0 rows of Qh and Kh from cls linear outputs.
// ---------------------------------------------------------------------------
__global__ __launch_bounds__(768) void cls_fill_kernel(
    const float* __restrict__ clsq, const float* __restrict__ clsk,
    f16* __restrict__ Qh, f16* __restrict__ Kh) {
  const int b = blockIdx.x;
  const int c = threadIdx.x;
  Qh[(((size_t)(b * NHEADS + (c >> 6))) * TQP) * 64 + (c & 63)] =
      (f16)clsq[b * CDIM + c];
  Kh[(((size_t)(b * NHEADS + (c >> 6))) * TKP) * 64 + (c & 63)] =
      (f16)clsk[b * CDIM + c];
}

// ---------------------------------------------------------------------------
// MFMA flash attention. Grid (13, 12, 8), 256 threads = 4 waves.
// ---------------------------------------------------------------------------
__global__ __launch_bounds__(256) void attn_mfma_kernel(
    const f16* __restrict__ Qh, const f16* __restrict__ Kh,
    const f16* __restrict__ Vht, f16* __restrict__ o16) {
  __shared__ __align__(16) f16 Ks[64 * 72];   // [key][d], pad 8
  __shared__ __align__(16) f16 Vt[64 * 72];   // [d][key], pad 8
  const int qt = blockIdx.x, h = blockIdx.y, b = blockIdx.z;
  const int tid = threadIdx.x;
  const int lane = tid & 63;
  const int w = tid >> 6;
  const int l15 = lane & 15, l4 = lane >> 4;
  const int q0 = qt * 128 + w * 32;

  const f16* Qp = Qh + ((size_t)(b * NHEADS + h) * TQP) * 64;
  const f16* Kp = Kh + ((size_t)(b * NHEADS + h) * TKP) * 64;
  const f16* Vp = Vht + ((size_t)(b * NHEADS + h) * 64) * TKP;

  f16x8_t bq[2][2];
#pragma unroll
  for (int qi = 0; qi < 2; qi++)
#pragma unroll
    for (int kf = 0; kf < 2; kf++)
      bq[qi][kf] = *(const f16x8_t*)(Qp + (size_t)(q0 + qi * 16 + l15) * 64 +
                                     kf * 32 + l4 * 8);

  f32x4_t oacc[4][2];
#pragma unroll
  for (int df = 0; df < 4; df++)
#pragma unroll
    for (int qi = 0; qi < 2; qi++) oacc[df][qi] = (f32x4_t){0.f, 0.f, 0.f, 0.f};
  float mrow[2] = {-1e30f, -1e30f};
  float lrow[2] = {0.f, 0.f};

  const int sr = tid >> 2, sc = (tid & 3) * 16;

  for (int kv0 = 0; kv0 < TKP; kv0 += 64) {
    const f16* kg = Kp + (size_t)(kv0 + sr) * 64 + sc;
    uint4 kl0 = *(const uint4*)kg;
    uint4 kl1 = *(const uint4*)(kg + 8);
    const f16* vg = Vp + (size_t)sr * TKP + kv0 + sc;
    uint4 vl0 = *(const uint4*)vg;
    uint4 vl1 = *(const uint4*)(vg + 8);
    __syncthreads();
    *(uint4*)(Ks + sr * 72 + sc) = kl0;
    *(uint4*)(Ks + sr * 72 + sc + 8) = kl1;
    *(uint4*)(Vt + sr * 72 + sc) = vl0;
    *(uint4*)(Vt + sr * 72 + sc + 8) = vl1;
    __syncthreads();

    f32x4_t sacc[4][2];
#pragma unroll
    for (int ki = 0; ki < 4; ki++)
#pragma unroll
      for (int qi = 0; qi < 2; qi++) sacc[ki][qi] = (f32x4_t){0.f, 0.f, 0.f, 0.f};
#pragma unroll
    for (int kf = 0; kf < 2; kf++) {
#pragma unroll
      for (int ki = 0; ki < 4; ki++) {
        f16x8_t ak =
            *(const f16x8_t*)(Ks + (ki * 16 + l15) * 72 + kf * 32 + l4 * 8);
#pragma unroll
        for (int qi = 0; qi < 2; qi++)
          sacc[ki][qi] = __builtin_amdgcn_mfma_f32_16x16x32_f16(
              ak, bq[qi][kf], sacc[ki][qi], 0, 0, 0);
      }
    }

    float pmax[2] = {-1e30f, -1e30f};
#pragma unroll
    for (int ki = 0; ki < 4; ki++) {
      const int keyb = kv0 + ki * 16 + l4 * 4;
#pragma unroll
      for (int qi = 0; qi < 2; qi++) {
#pragma unroll
        for (int rr = 0; rr < 4; rr++) {
          float s = sacc[ki][qi][rr] * ATTN_SCALE;
          if (keyb + rr >= NKTOK) s = -1e30f;
          sacc[ki][qi][rr] = s;
          pmax[qi] = fmaxf(pmax[qi], s);
        }
      }
    }
#pragma unroll
    for (int qi = 0; qi < 2; qi++) {
      pmax[qi] = fmaxf(pmax[qi], __shfl_xor(pmax[qi], 16, 64));
      pmax[qi] = fmaxf(pmax[qi], __shfl_xor(pmax[qi], 32, 64));
      float mnew = fmaxf(mrow[qi], pmax[qi]);
      float alpha = __expf(mrow[qi] - mnew);
      mrow[qi] = mnew;
      lrow[qi] *= alpha;
#pragma unroll
      for (int df = 0; df < 4; df++) {
        oacc[df][qi][0] *= alpha;
        oacc[df][qi][1] *= alpha;
        oacc[df][qi][2] *= alpha;
        oacc[df][qi][3] *= alpha;
      }
    }
    f16x4_t pb[4][2];
#pragma unroll
    for (int ki = 0; ki < 4; ki++) {
#pragma unroll
      for (int qi = 0; qi < 2; qi++) {
        float p0 = __expf(sacc[ki][qi][0] - mrow[qi]);
        float p1 = __expf(sacc[ki][qi][1] - mrow[qi]);
        float p2 = __expf(sacc[ki][qi][2] - mrow[qi]);
        float p3 = __expf(sacc[ki][qi][3] - mrow[qi]);
        lrow[qi] += p0 + p1 + p2 + p3;
        f16x4_t pv = {(f16)p0, (f16)p1, (f16)p2, (f16)p3};
        pb[ki][qi] = pv;
      }
    }

#pragma unroll
    for (int df = 0; df < 4; df++) {
#pragma unroll
      for (int ki = 0; ki < 4; ki++) {
        f16x4_t av =
            *(const f16x4_t*)(Vt + (df * 16 + l15) * 72 + ki * 16 + l4 * 4);
#pragma unroll
        for (int qi = 0; qi < 2; qi++)
          oacc[df][qi] = __builtin_amdgcn_mfma_f32_16x16x16f16(
              av, pb[ki][qi], oacc[df][qi], 0, 0, 0);
      }
    }
  }

  float inv[2];
#pragma unroll
  for (int qi = 0; qi < 2; qi++) {
    float l = lrow[qi];
    l += __shfl_xor(l, 16, 64);
    l += __shfl_xor(l, 32, 64);
    inv[qi] = 1.f / l;
  }
#pragma unroll
  for (int qi = 0; qi < 2; qi++) {
    const int q = q0 + qi * 16 + l15;
    if (q < NQTOK) {
      f16* op = o16 + ((size_t)(b * NQTOK + q)) * CDIM + h * 64 + l4 * 4;
#pragma unroll
      for (int df = 0; df < 4; df++) {
        f16x4_t ov = {(f16)(oacc[df][qi][0] * inv[qi]),
                      (f16)(oacc[df][qi][1] * inv[qi]),
                      (f16)(oacc[df][qi][2] * inv[qi]),
                      (f16)(oacc[df][qi][3] * inv[qi])};
        *(f16x4_t*)(op + df * 16) = ov;
      }
    }
  }
}

// ---------------------------------------------------------------------------
extern "C" void kernel_launch(void* const* d_in, const int* in_sizes, int n_in,
                              void* d_out, int out_size, void* d_ws, size_t ws_size,
                              hipStream_t stream) {
  const float* x      = (const float*)d_in[0];
  const float* cls    = (const float*)d_in[1];
  const float* Wq     = (const float*)d_in[2];
  const float* bq     = (const float*)d_in[3];
  const float* Wk     = (const float*)d_in[4];
  const float* bk     = (const float*)d_in[5];
  const float* Wv     = (const float*)d_in[6];
  const float* bv     = (const float*)d_in[7];
  const float* conv_q = (const float*)d_in[8];
  const float* conv_k = (const float*)d_in[9];
  const float* conv_v = (const float*)d_in[10];
  const float* lnq_w  = (const float*)d_in[11];
  const float* lnq_b  = (const float*)d_in[12];
  const float* lnk_w  = (const float*)d_in[13];
  const float* lnk_b  = (const float*)d_in[14];
  const float* lnv_w  = (const float*)d_in[15];
  const float* lnv_b  = (const float*)d_in[16];
  const float* Wproj  = (const float*)d_in[17];
  const float* bproj  = (const float*)d_in[18];

  // Workspace layout (bytes), all f16 intermediates. Total ≈ 103.7 MB.
  char* wsb = (char*)d_ws;
  f16*   Xt     = (f16*)(wsb + 0);           // 20,447,232
  f16*   W16    = (f16*)(wsb + 20447232);    //  4,718,592
  f16*   q_lin  = (f16*)(wsb + 25165824);    // 19,267,584
  f16*   k_lin  = (f16*)(wsb + 44433408);    // 19,267,584
  f16*   v_lin  = (f16*)(wsb + 63700992);    // 19,267,584
  f16*   k_pool = (f16*)(wsb + 82968576);    //  4,816,896
  f16*   v_pool = (f16*)(wsb + 87785472);    //  4,816,896
  float* clsq   = (float*)(wsb + 92602368);  //  3 x 24,576 contiguous
  float* clsk   = (float*)(wsb + 92626944);
  float* clsv   = (float*)(wsb + 92651520);
  f16*   Kh     = (f16*)(wsb + 92676096);    //  5,505,024
  f16*   Vht    = (f16*)(wsb + 98181120);    //  5,505,024 -> end 103,686,144
  f16*   q_pool = k_lin;        // alias: k_lin dead after dwconv_k
  f16*   Qh     = Xt;           // alias: Xt dead after QKV GEMM
  f16*   o16    = v_lin;        // alias: v_lin (+k_pool head) dead by attn

  f16* W16p = W16 + (size_t)3 * WELEM;

  // 1. convert weights to fp16 (one launch)
  convert4_kernel<<<dim3(576, 4), 256, 0, stream>>>(Wq, Wk, Wv, Wproj, W16);

  // 2. transpose+convert X -> Xt
  transpose_x_kernel<<<dim3(52, 24, BATCH), 256, 0, stream>>>(x, Xt);

  // 3. fused QKV MFMA GEMM (global_load_lds staging) -> f16 lin buffers
  gemm_qkv_f16_kernel<<<1872, 256, 0, stream>>>(W16, Xt, bq, bk, bv, q_lin);

  // 4. cls token linears (one launch)
  cls_linear3_kernel<<<dim3(BATCH, 3), 256, 0, stream>>>(cls, Wq, Wk, Wv, bq,
                                                         bk, bv, clsq);

  // 5. depthwise convs (k first, then q overwrites k_lin via alias)
  dwconv_kernel<<<BATCH * CDIM, 256, 0, stream>>>(k_lin, conv_k, k_pool,
                                                  8, 7, 7, 2, 2);
  dwconv_kernel<<<BATCH * CDIM, 256, 0, stream>>>(v_lin, conv_v, v_pool,
                                                  8, 7, 7, 2, 2);
  dwconv_kernel<<<BATCH * CDIM, 256, 0, stream>>>(q_lin, conv_q, q_pool,
                                                  8, 14, 14, 1, 1);

  // 6. fused LN + pack
  ln_pack_qk_kernel<<<dim3(49, BATCH), 256, 0, stream>>>(q_pool, lnq_w, lnq_b,
                                                         Qh, NSP, TQP);
  ln_pack_qk_kernel<<<dim3(13, BATCH), 256, 0, stream>>>(k_pool, lnk_w, lnk_b,
                                                         Kh, NKSP, TKP);
  ln_pack_v_kernel<<<dim3(14, BATCH), 256, 0, stream>>>(v_pool, clsv, lnv_w,
                                                        lnv_b, Vht);
  cls_fill_kernel<<<BATCH, 768, 0, stream>>>(clsq, clsk, Qh, Kh);

  // 7. MFMA attention -> o16
  attn_mfma_kernel<<<dim3(13, NHEADS, BATCH), 256, 0, stream>>>(Qh, Kh, Vht,
                                                                o16);

  // 8. projection MFMA GEMM (bijective XCD swizzle) -> d_out
  float* xo = (float*)d_out;
  float* cls_o = (float*)d_out + (size_t)BATCH * CDIM * NSP;
  gemm_proj_f16_kernel<<<594, 256, 0, stream>>>(W16p, o16, bproj, xo, cls_o);
}